// Round 2
// baseline (637.919 us; speedup 1.0000x reference)
//
#include <hip/hip_runtime.h>
#include <math.h>

typedef __bf16 bf16;
typedef __bf16 bf16x8 __attribute__((ext_vector_type(8)));
typedef float f32x4 __attribute__((ext_vector_type(4)));

#define N_TOK 2048
#define DMODEL 768
#define NHEAD 12
#define TSEQ 1024
#define NEXP 8
#define DFF 3072

__device__ inline f32x4 mfma16(bf16x8 a, bf16x8 b, f32x4 c) {
    return __builtin_amdgcn_mfma_f32_16x16x32_bf16(a, b, c, 0, 0, 0);
}

__device__ inline f32x4 zero4() { f32x4 z = {0.f, 0.f, 0.f, 0.f}; return z; }

// ---------------- block reduction (256 threads = 4 waves) ----------------
__device__ inline float block_sum(float v, float* red, int tid) {
#pragma unroll
    for (int off = 32; off > 0; off >>= 1) v += __shfl_down(v, off, 64);
    __syncthreads();
    if ((tid & 63) == 0) red[tid >> 6] = v;
    __syncthreads();
    return red[0] + red[1] + red[2] + red[3];
}

// ---------------- LN1: x -> bf16 hi/lo pair ----------------
__global__ __launch_bounds__(256) void ln1_kernel(const float* __restrict__ x,
        const float* __restrict__ g, const float* __restrict__ b,
        bf16* __restrict__ hh, bf16* __restrict__ hl) {
    __shared__ float red[4];
    int row = blockIdx.x, tid = threadIdx.x;
    const float* xr = x + (size_t)row * DMODEL;
    float v[3];
#pragma unroll
    for (int i = 0; i < 3; i++) v[i] = xr[tid + i * 256];
    float s = block_sum(v[0] + v[1] + v[2], red, tid);
    float mu = s * (1.f / DMODEL);
    float q = 0.f;
#pragma unroll
    for (int i = 0; i < 3; i++) { float d = v[i] - mu; q += d * d; }
    q = block_sum(q, red, tid);
    float rstd = 1.0f / sqrtf(q * (1.f / DMODEL) + 1e-5f);
#pragma unroll
    for (int i = 0; i < 3; i++) {
        int d = tid + i * 256;
        float val = (v[i] - mu) * rstd * g[d] + b[d];
        bf16 hi = (bf16)val;
        hh[(size_t)row * DMODEL + d] = hi;
        hl[(size_t)row * DMODEL + d] = (bf16)(val - (float)hi);
    }
}

// ---------------- shared GEMM pieces ----------------
// LDS tiles: A [128 rows][32 k] stride 40, Bt [128 cols][32 k] stride 40.
// MFMA 16x16x32: A-frag lane reads A[m=lane&15][k=quad*8+j];
// B-frag lane reads Bt[n=lane&15][k=quad*8+j]; C/D: col=lane&15,row=quad*4+reg.
__device__ inline void gemm_step3(const bf16* lah, const bf16* lal,
                                  const bf16* lbh, const bf16* lbl,
                                  int wm, int wn, int row16, int quad,
                                  f32x4 acc[4][4]) {
    bf16x8 ah[4], al[4], bh[4], bl[4];
#pragma unroll
    for (int i = 0; i < 4; i++) {
        int ro = (wm * 64 + i * 16 + row16) * 40 + quad * 8;
        ah[i] = *(const bf16x8*)&lah[ro];
        al[i] = *(const bf16x8*)&lal[ro];
    }
#pragma unroll
    for (int i = 0; i < 4; i++) {
        int ro = (wn * 64 + i * 16 + row16) * 40 + quad * 8;
        bh[i] = *(const bf16x8*)&lbh[ro];
        bl[i] = *(const bf16x8*)&lbl[ro];
    }
#pragma unroll
    for (int mi = 0; mi < 4; mi++)
#pragma unroll
        for (int ni = 0; ni < 4; ni++) {
            acc[mi][ni] = mfma16(ah[mi], bh[ni], acc[mi][ni]);
            acc[mi][ni] = mfma16(ah[mi], bl[ni], acc[mi][ni]);
            acc[mi][ni] = mfma16(al[mi], bh[ni], acc[mi][ni]);
        }
}

__device__ inline void gemm_step1(const bf16* la, const bf16* lb, int wm, int wn,
                                  int row16, int quad, f32x4 acc[4][4]) {
    bf16x8 af[4], bfr[4];
#pragma unroll
    for (int i = 0; i < 4; i++)
        af[i] = *(const bf16x8*)&la[(wm * 64 + i * 16 + row16) * 40 + quad * 8];
#pragma unroll
    for (int i = 0; i < 4; i++)
        bfr[i] = *(const bf16x8*)&lb[(wn * 64 + i * 16 + row16) * 40 + quad * 8];
#pragma unroll
    for (int mi = 0; mi < 4; mi++)
#pragma unroll
        for (int ni = 0; ni < 4; ni++)
            acc[mi][ni] = mfma16(af[mi], bfr[ni], acc[mi][ni]);
}

__device__ inline void stage_A(bf16* la, const bf16* Abase, int lda, int k0, int tid) {
#pragma unroll
    for (int i = 0; i < 2; i++) {
        int chunk = tid + i * 256;          // 512 chunks of 8 elems = 128x32
        int r = chunk >> 2, c = (chunk & 3) << 3;
        *(bf16x8*)&la[r * 40 + c] = *(const bf16x8*)&Abase[(size_t)r * lda + k0 + c];
    }
}

// ---------------- QKV GEMM (split bf16x3): -> q/k/v hi/lo [B,H,T,HS] ----------------
__global__ __launch_bounds__(256) void qkv_gemm(const bf16* __restrict__ hA_h,
        const bf16* __restrict__ hA_l,
        const float* __restrict__ Wq, const float* __restrict__ Wk,
        const float* __restrict__ Wv,
        bf16* __restrict__ qh, bf16* __restrict__ ql,
        bf16* __restrict__ kh, bf16* __restrict__ kl,
        bf16* __restrict__ vh, bf16* __restrict__ vl) {
    __shared__ alignas(16) bf16 lah[128 * 40];
    __shared__ alignas(16) bf16 lal[128 * 40];
    __shared__ alignas(16) bf16 lbh[128 * 40];
    __shared__ alignas(16) bf16 lbl[128 * 40];
    int tid = threadIdx.x;
    int m0 = blockIdx.y * 128;
    int nt = blockIdx.x;                 // 0..17 -> 6 tiles each of q,k,v
    int sel = nt / 6;
    int n0 = (nt % 6) * 128;
    const float* W = (sel == 0) ? Wq : (sel == 1) ? Wk : Wv;
    bf16* obh = (sel == 0) ? qh : (sel == 1) ? kh : vh;
    bf16* obl = (sel == 0) ? ql : (sel == 1) ? kl : vl;
    int lane = tid & 63, w = tid >> 6, row16 = lane & 15, quad = lane >> 4;
    int wm = w >> 1, wn = w & 1;
    f32x4 acc[4][4];
#pragma unroll
    for (int mi = 0; mi < 4; mi++)
#pragma unroll
        for (int ni = 0; ni < 4; ni++) acc[mi][ni] = zero4();
    const bf16* Arow_h = hA_h + (size_t)m0 * DMODEL;
    const bf16* Arow_l = hA_l + (size_t)m0 * DMODEL;
    for (int k0 = 0; k0 < DMODEL; k0 += 32) {
        __syncthreads();
        stage_A(lah, Arow_h, DMODEL, k0, tid);
        stage_A(lal, Arow_l, DMODEL, k0, tid);
#pragma unroll
        for (int i = 0; i < 16; i++) {
            int idx = tid + (i << 8);
            int k = idx >> 7, n = idx & 127;
            int col = n0 + n;
            float val = W[((size_t)(col >> 6) * DMODEL + k0 + k) * 64 + (col & 63)];
            bf16 hi = (bf16)val;
            lbh[n * 40 + k] = hi;
            lbl[n * 40 + k] = (bf16)(val - (float)hi);
        }
        __syncthreads();
        gemm_step3(lah, lal, lbh, lbl, wm, wn, row16, quad, acc);
    }
#pragma unroll
    for (int mi = 0; mi < 4; mi++) {
        int rowl = wm * 64 + mi * 16 + quad * 4;
#pragma unroll
        for (int ni = 0; ni < 4; ni++) {
            int col = n0 + wn * 64 + ni * 16 + row16;
            int hhd = col >> 6, s = col & 63;
#pragma unroll
            for (int r = 0; r < 4; r++) {
                int gm = m0 + rowl + r;
                int bb = gm >> 10, t = gm & 1023;
                size_t oi = (((size_t)bb * NHEAD + hhd) * TSEQ + t) * 64 + s;
                float val = acc[mi][ni][r];
                bf16 hi = (bf16)val;
                obh[oi] = hi;
                obl[oi] = (bf16)(val - (float)hi);
            }
        }
    }
}

// ---------------- flash attention (split bf16x3), causal, scale = 768^-0.5 ----------------
__global__ __launch_bounds__(256) void attn_kernel(const bf16* __restrict__ qhb,
        const bf16* __restrict__ qlb, const bf16* __restrict__ khb,
        const bf16* __restrict__ klb, const bf16* __restrict__ vhb,
        const bf16* __restrict__ vlb, bf16* __restrict__ aoh,
        bf16* __restrict__ aol) {
    __shared__ alignas(16) bf16 kt_h[64 * 72];
    __shared__ alignas(16) bf16 kt_l[64 * 72];
    __shared__ alignas(16) bf16 vt_h[64 * 72];
    __shared__ alignas(16) bf16 vt_l[64 * 72];
    __shared__ alignas(16) bf16 p_h[4][16 * 72];
    __shared__ alignas(16) bf16 p_l[4][16 * 72];
    int qt = blockIdx.x, bh = blockIdx.y;
    int b = bh / NHEAD, hh = bh % NHEAD;
    int tid = threadIdx.x, lane = tid & 63, w = tid >> 6;
    int row16 = lane & 15, quad = lane >> 4;
    const bf16* qph = qhb + (size_t)bh * TSEQ * 64;
    const bf16* qpl = qlb + (size_t)bh * TSEQ * 64;
    const bf16* kph = khb + (size_t)bh * TSEQ * 64;
    const bf16* kpl = klb + (size_t)bh * TSEQ * 64;
    const bf16* vph = vhb + (size_t)bh * TSEQ * 64;
    const bf16* vpl = vlb + (size_t)bh * TSEQ * 64;
    int qrow = qt * 64 + w * 16 + row16;
    bf16x8 aq_h[2], aq_l[2];
#pragma unroll
    for (int kk = 0; kk < 2; kk++) {
        aq_h[kk] = *(const bf16x8*)&qph[(size_t)qrow * 64 + kk * 32 + quad * 8];
        aq_l[kk] = *(const bf16x8*)&qpl[(size_t)qrow * 64 + kk * 32 + quad * 8];
    }
    f32x4 o[4];
    float m_i[4], l_i[4];
#pragma unroll
    for (int i = 0; i < 4; i++) { o[i] = zero4(); m_i[i] = -INFINITY; l_i[i] = 0.f; }
    const float sc = 0.03608439182435161f;  // 768^-0.5
    for (int kt = 0; kt <= qt; kt++) {
        __syncthreads();
#pragma unroll
        for (int i = 0; i < 2; i++) {
            int chunk = tid + i * 256;      // 512 chunks of 8 = 64x64
            int r = chunk >> 3, c = (chunk & 7) << 3;
            size_t gi = (size_t)(kt * 64 + r) * 64 + c;
            *(bf16x8*)&kt_h[r * 72 + c] = *(const bf16x8*)&kph[gi];
            *(bf16x8*)&kt_l[r * 72 + c] = *(const bf16x8*)&kpl[gi];
        }
#pragma unroll
        for (int i = 0; i < 16; i++) {
            int idx = tid + (i << 8);
            int tk = idx >> 6, s = idx & 63;
            size_t gi = (size_t)(kt * 64 + tk) * 64 + s;
            vt_h[s * 72 + tk] = vph[gi];
            vt_l[s * 72 + tk] = vpl[gi];
        }
        __syncthreads();
        f32x4 sacc[4];
#pragma unroll
        for (int ni = 0; ni < 4; ni++) {
            sacc[ni] = zero4();
#pragma unroll
            for (int kk = 0; kk < 2; kk++) {
                int ro = (ni * 16 + row16) * 72 + kk * 32 + quad * 8;
                bf16x8 bk_h = *(const bf16x8*)&kt_h[ro];
                bf16x8 bk_l = *(const bf16x8*)&kt_l[ro];
                sacc[ni] = mfma16(aq_h[kk], bk_h, sacc[ni]);
                sacc[ni] = mfma16(aq_h[kk], bk_l, sacc[ni]);
                sacc[ni] = mfma16(aq_l[kk], bk_h, sacc[ni]);
            }
        }
        float mrow[4];
#pragma unroll
        for (int r = 0; r < 4; r++) mrow[r] = -INFINITY;
        int tq_b = qt * 64 + w * 16 + quad * 4;
#pragma unroll
        for (int ni = 0; ni < 4; ni++) {
            int tkg = kt * 64 + ni * 16 + row16;   // column = key index
#pragma unroll
            for (int r = 0; r < 4; r++) {
                float sv = sacc[ni][r] * sc;
                if (tkg > tq_b + r) sv = -INFINITY;
                sacc[ni][r] = sv;
                mrow[r] = fmaxf(mrow[r], sv);
            }
        }
#pragma unroll
        for (int r = 0; r < 4; r++) {
#pragma unroll
            for (int off = 8; off > 0; off >>= 1)
                mrow[r] = fmaxf(mrow[r], __shfl_xor(mrow[r], off, 16));
        }
        float alpha[4], rsum[4];
#pragma unroll
        for (int r = 0; r < 4; r++) {
            float nm = fmaxf(m_i[r], mrow[r]);
            alpha[r] = __expf(m_i[r] - nm);
            m_i[r] = nm;
            rsum[r] = 0.f;
        }
#pragma unroll
        for (int ni = 0; ni < 4; ni++)
#pragma unroll
            for (int r = 0; r < 4; r++) {
                float p = __expf(sacc[ni][r] - m_i[r]);
                sacc[ni][r] = p;
                rsum[r] += p;
            }
#pragma unroll
        for (int r = 0; r < 4; r++) {
#pragma unroll
            for (int off = 8; off > 0; off >>= 1)
                rsum[r] += __shfl_xor(rsum[r], off, 16);
            l_i[r] = l_i[r] * alpha[r] + rsum[r];
        }
#pragma unroll
        for (int ni = 0; ni < 4; ni++)
#pragma unroll
            for (int r = 0; r < 4; r++) o[ni][r] *= alpha[r];
        // P (C-layout, fp32) -> split -> LDS -> A-layout
#pragma unroll
        for (int ni = 0; ni < 4; ni++)
#pragma unroll
            for (int r = 0; r < 4; r++) {
                float p = sacc[ni][r];
                bf16 hi = (bf16)p;
                int po = (quad * 4 + r) * 72 + ni * 16 + row16;
                p_h[w][po] = hi;
                p_l[w][po] = (bf16)(p - (float)hi);
            }
        __syncthreads();
        bf16x8 ap_h[2], ap_l[2];
#pragma unroll
        for (int kk = 0; kk < 2; kk++) {
            ap_h[kk] = *(const bf16x8*)&p_h[w][row16 * 72 + kk * 32 + quad * 8];
            ap_l[kk] = *(const bf16x8*)&p_l[w][row16 * 72 + kk * 32 + quad * 8];
        }
#pragma unroll
        for (int ni = 0; ni < 4; ni++)
#pragma unroll
            for (int kk = 0; kk < 2; kk++) {
                int ro = (ni * 16 + row16) * 72 + kk * 32 + quad * 8;
                bf16x8 bv_h = *(const bf16x8*)&vt_h[ro];
                bf16x8 bv_l = *(const bf16x8*)&vt_l[ro];
                o[ni] = mfma16(ap_h[kk], bv_h, o[ni]);
                o[ni] = mfma16(ap_h[kk], bv_l, o[ni]);
                o[ni] = mfma16(ap_l[kk], bv_h, o[ni]);
            }
    }
    int t = qt * 64 + w * 16 + quad * 4;
#pragma unroll
    for (int ni = 0; ni < 4; ni++) {
        int col = hh * 64 + ni * 16 + row16;
#pragma unroll
        for (int r = 0; r < 4; r++) {
            float val = o[ni][r] / l_i[r];
            size_t n = (size_t)b * TSEQ + t + r;
            bf16 hi = (bf16)val;
            aoh[n * DMODEL + col] = hi;
            aol[n * DMODEL + col] = (bf16)(val - (float)hi);
        }
    }
}

// ---------------- proj GEMM (split bf16x3): attnout @ Wp + bp + x -> x1 (fp32) ----------------
__global__ __launch_bounds__(256) void proj_gemm(const bf16* __restrict__ aInH,
        const bf16* __restrict__ aInL,
        const float* __restrict__ Wp, const float* __restrict__ bp,
        const float* __restrict__ x, float* __restrict__ x1) {
    __shared__ alignas(16) bf16 lah[128 * 40];
    __shared__ alignas(16) bf16 lal[128 * 40];
    __shared__ alignas(16) bf16 lbh[128 * 40];
    __shared__ alignas(16) bf16 lbl[128 * 40];
    int tid = threadIdx.x;
    int m0 = blockIdx.y * 128, n0 = blockIdx.x * 128;
    int lane = tid & 63, w = tid >> 6, row16 = lane & 15, quad = lane >> 4;
    int wm = w >> 1, wn = w & 1;
    f32x4 acc[4][4];
#pragma unroll
    for (int mi = 0; mi < 4; mi++)
#pragma unroll
        for (int ni = 0; ni < 4; ni++) acc[mi][ni] = zero4();
    const bf16* Arow_h = aInH + (size_t)m0 * DMODEL;
    const bf16* Arow_l = aInL + (size_t)m0 * DMODEL;
    for (int k0 = 0; k0 < DMODEL; k0 += 32) {
        __syncthreads();
        stage_A(lah, Arow_h, DMODEL, k0, tid);
        stage_A(lal, Arow_l, DMODEL, k0, tid);
#pragma unroll
        for (int i = 0; i < 16; i++) {
            int idx = tid + (i << 8);
            int kk = idx >> 7, n = idx & 127;
            float val = Wp[(size_t)(k0 + kk) * DMODEL + n0 + n];
            bf16 hi = (bf16)val;
            lbh[n * 40 + kk] = hi;
            lbl[n * 40 + kk] = (bf16)(val - (float)hi);
        }
        __syncthreads();
        gemm_step3(lah, lal, lbh, lbl, wm, wn, row16, quad, acc);
    }
#pragma unroll
    for (int mi = 0; mi < 4; mi++) {
        int rowl = wm * 64 + mi * 16 + quad * 4;
#pragma unroll
        for (int ni = 0; ni < 4; ni++) {
            int col = n0 + wn * 64 + ni * 16 + row16;
#pragma unroll
            for (int r = 0; r < 4; r++) {
                int gm = m0 + rowl + r;
                x1[(size_t)gm * DMODEL + col] =
                    acc[mi][ni][r] + bp[col] + x[(size_t)gm * DMODEL + col];
            }
        }
    }
}

// ---------------- LN2 + gate argmax + expert counting ----------------
__global__ __launch_bounds__(256) void ln2_gate_kernel(const float* __restrict__ x1,
        const float* __restrict__ g, const float* __restrict__ b,
        const float* __restrict__ Wg, bf16* __restrict__ h2,
        int* __restrict__ sel, int* __restrict__ counts) {
    __shared__ float red[4];
    __shared__ float glog[8];
    int row = blockIdx.x, tid = threadIdx.x;
    if (tid < 8) glog[tid] = 0.f;
    const float* xr = x1 + (size_t)row * DMODEL;
    float v[3];
#pragma unroll
    for (int i = 0; i < 3; i++) v[i] = xr[tid + i * 256];
    float s = block_sum(v[0] + v[1] + v[2], red, tid);
    float mu = s * (1.f / DMODEL);
    float qv = 0.f;
#pragma unroll
    for (int i = 0; i < 3; i++) { float d = v[i] - mu; qv += d * d; }
    qv = block_sum(qv, red, tid);
    float rstd = 1.0f / sqrtf(qv * (1.f / DMODEL) + 1e-5f);
    float ga[8];
#pragma unroll
    for (int e = 0; e < 8; e++) ga[e] = 0.f;
#pragma unroll
    for (int i = 0; i < 3; i++) {
        int d = tid + i * 256;
        float hv = (v[i] - mu) * rstd * g[d] + b[d];
        h2[(size_t)row * DMODEL + d] = (bf16)hv;
        const float* wgr = Wg + (size_t)d * NEXP;
#pragma unroll
        for (int e = 0; e < 8; e++) ga[e] += hv * wgr[e];
    }
#pragma unroll
    for (int e = 0; e < 8; e++)
#pragma unroll
        for (int off = 32; off > 0; off >>= 1) ga[e] += __shfl_down(ga[e], off, 64);
    if ((tid & 63) == 0)
#pragma unroll
        for (int e = 0; e < 8; e++) atomicAdd(&glog[e], ga[e]);
    __syncthreads();
    if (tid == 0) {
        float best = glog[0];
        int bi = 0;
#pragma unroll
        for (int e = 1; e < 8; e++)
            if (glog[e] > best) { best = glog[e]; bi = e; }  // strict > keeps lowest idx on tie
        sel[row] = bi;
        atomicAdd(&counts[bi], 1);
    }
}

// ---------------- routing helpers ----------------
__global__ void zero_kernel(int* __restrict__ p, int n) {
    int i = blockIdx.x * blockDim.x + threadIdx.x;
    if (i < n) p[i] = 0;
}
__global__ void scan_kernel(const int* __restrict__ counts, int* __restrict__ offsets) {
    if (threadIdx.x == 0) {
        int o = 0;
        for (int e = 0; e < NEXP; e++) { offsets[e] = o; o += counts[e]; }
    }
}
__global__ void scatter_kernel(const int* __restrict__ sel, const int* __restrict__ offsets,
                               int* __restrict__ cursor, int* __restrict__ perm) {
    int n = blockIdx.x * blockDim.x + threadIdx.x;
    if (n >= N_TOK) return;
    int e = sel[n];
    int pos = atomicAdd(&cursor[e], 1);
    perm[offsets[e] + pos] = n;
}

// ---------------- MoE GEMM1: hid = relu(h2[perm] @ W1[e] + b1[e]) ----------------
__global__ __launch_bounds__(256) void moe1_gemm(const bf16* __restrict__ h2,
        const float* __restrict__ W1, const float* __restrict__ b1,
        const int* __restrict__ counts, const int* __restrict__ offsets,
        const int* __restrict__ perm, bf16* __restrict__ hid) {
    int e = blockIdx.z;
    int cnt = counts[e];
    int rt = blockIdx.y;
    if (rt * 128 >= cnt) return;
    int off = offsets[e];
    int n0 = blockIdx.x * 128;
    const float* W = W1 + (size_t)e * DMODEL * DFF;
    __shared__ alignas(16) bf16 la[128 * 40];
    __shared__ alignas(16) bf16 lb[128 * 40];
    int tid = threadIdx.x;
    int lane = tid & 63, w = tid >> 6, row16 = lane & 15, quad = lane >> 4;
    int wm = w >> 1, wn = w & 1;
    int r_a = tid >> 2, c_a = (tid & 3) << 3;
    int tok0 = perm[off + min(rt * 128 + r_a, cnt - 1)];
    int tok1 = perm[off + min(rt * 128 + r_a + 64, cnt - 1)];
    f32x4 acc[4][4];
#pragma unroll
    for (int mi = 0; mi < 4; mi++)
#pragma unroll
        for (int ni = 0; ni < 4; ni++) acc[mi][ni] = zero4();
    for (int k0 = 0; k0 < DMODEL; k0 += 32) {
        __syncthreads();
        *(bf16x8*)&la[r_a * 40 + c_a] = *(const bf16x8*)&h2[(size_t)tok0 * DMODEL + k0 + c_a];
        *(bf16x8*)&la[(r_a + 64) * 40 + c_a] = *(const bf16x8*)&h2[(size_t)tok1 * DMODEL + k0 + c_a];
#pragma unroll
        for (int i = 0; i < 16; i++) {
            int idx = tid + (i << 8);
            int kk = idx >> 7, n = idx & 127;
            lb[n * 40 + kk] = (bf16)W[(size_t)(k0 + kk) * DFF + n0 + n];
        }
        __syncthreads();
        gemm_step1(la, lb, wm, wn, row16, quad, acc);
    }
#pragma unroll
    for (int mi = 0; mi < 4; mi++) {
        int rowl = wm * 64 + mi * 16 + quad * 4;
#pragma unroll
        for (int ni = 0; ni < 4; ni++) {
            int col = n0 + wn * 64 + ni * 16 + row16;
#pragma unroll
            for (int r = 0; r < 4; r++) {
                int lr = rowl + r;
                if (rt * 128 + lr < cnt) {
                    float val = acc[mi][ni][r] + b1[(size_t)e * DFF + col];
                    val = fmaxf(val, 0.f);
                    hid[(size_t)(off + rt * 128 + lr) * DFF + col] = (bf16)val;
                }
            }
        }
    }
}

// ---------------- MoE GEMM2: out = x1 + hid @ W2[e] + b2[e] (scatter rows) ----------------
__global__ __launch_bounds__(256) void moe2_gemm(const bf16* __restrict__ hid,
        const float* __restrict__ W2, const float* __restrict__ b2,
        const int* __restrict__ counts, const int* __restrict__ offsets,
        const int* __restrict__ perm, const float* __restrict__ x1,
        float* __restrict__ out) {
    int e = blockIdx.z;
    int cnt = counts[e];
    int rt = blockIdx.y;
    if (rt * 128 >= cnt) return;
    int off = offsets[e];
    int n0 = blockIdx.x * 128;
    const float* W = W2 + (size_t)e * DFF * DMODEL;
    __shared__ alignas(16) bf16 la[128 * 40];
    __shared__ alignas(16) bf16 lb[128 * 40];
    int tid = threadIdx.x;
    int lane = tid & 63, w = tid >> 6, row16 = lane & 15, quad = lane >> 4;
    int wm = w >> 1, wn = w & 1;
    int r_a = tid >> 2, c_a = (tid & 3) << 3;
    const bf16* arow0 = hid + (size_t)min(off + rt * 128 + r_a, N_TOK - 1) * DFF;
    const bf16* arow1 = hid + (size_t)min(off + rt * 128 + r_a + 64, N_TOK - 1) * DFF;
    f32x4 acc[4][4];
#pragma unroll
    for (int mi = 0; mi < 4; mi++)
#pragma unroll
        for (int ni = 0; ni < 4; ni++) acc[mi][ni] = zero4();
    for (int k0 = 0; k0 < DFF; k0 += 32) {
        __syncthreads();
        *(bf16x8*)&la[r_a * 40 + c_a] = *(const bf16x8*)&arow0[k0 + c_a];
        *(bf16x8*)&la[(r_a + 64) * 40 + c_a] = *(const bf16x8*)&arow1[k0 + c_a];
#pragma unroll
        for (int i = 0; i < 16; i++) {
            int idx = tid + (i << 8);
            int kk = idx >> 7, n = idx & 127;
            lb[n * 40 + kk] = (bf16)W[(size_t)(k0 + kk) * DMODEL + n0 + n];
        }
        __syncthreads();
        gemm_step1(la, lb, wm, wn, row16, quad, acc);
    }
#pragma unroll
    for (int mi = 0; mi < 4; mi++) {
        int rowl = wm * 64 + mi * 16 + quad * 4;
#pragma unroll
        for (int ni = 0; ni < 4; ni++) {
            int col = n0 + wn * 64 + ni * 16 + row16;
#pragma unroll
            for (int r = 0; r < 4; r++) {
                int lr = rowl + r;
                if (rt * 128 + lr < cnt) {
                    int n = perm[off + rt * 128 + lr];
                    out[(size_t)n * DMODEL + col] =
                        acc[mi][ni][r] + b2[(size_t)e * DMODEL + col] +
                        x1[(size_t)n * DMODEL + col];
                }
            }
        }
    }
}

// ---------------- launch ----------------
extern "C" void kernel_launch(void* const* d_in, const int* in_sizes, int n_in,
                              void* d_out, int out_size, void* d_ws, size_t ws_size,
                              hipStream_t stream) {
    const float* x    = (const float*)d_in[0];
    const float* ln1g = (const float*)d_in[1];
    const float* ln1b = (const float*)d_in[2];
    const float* ln2g = (const float*)d_in[3];
    const float* ln2b = (const float*)d_in[4];
    const float* Wq   = (const float*)d_in[5];
    const float* Wk   = (const float*)d_in[6];
    const float* Wv   = (const float*)d_in[7];
    const float* Wp   = (const float*)d_in[8];
    const float* bp   = (const float*)d_in[9];
    const float* Wg   = (const float*)d_in[10];
    const float* W1   = (const float*)d_in[11];
    const float* b1   = (const float*)d_in[12];
    const float* W2   = (const float*)d_in[13];
    const float* b2   = (const float*)d_in[14];
    float* out = (float*)d_out;

    char* ws = (char*)d_ws;
    size_t off = 0;
    const size_t SZ = (size_t)N_TOK * DMODEL * 2;   // 3 MB per bf16 buffer
    bf16* h1h = (bf16*)(ws + off); off += SZ;
    bf16* h1l = (bf16*)(ws + off); off += SZ;
    bf16* qh  = (bf16*)(ws + off); off += SZ;
    bf16* ql  = (bf16*)(ws + off); off += SZ;
    bf16* kh  = (bf16*)(ws + off); off += SZ;
    bf16* kl  = (bf16*)(ws + off); off += SZ;
    bf16* vh  = (bf16*)(ws + off); off += SZ;
    bf16* vl  = (bf16*)(ws + off); off += SZ;
    bf16* aoh = (bf16*)(ws + off); off += SZ;
    bf16* aol = (bf16*)(ws + off); off += SZ;
    float* x1 = (float*)(ws + off); off += (size_t)N_TOK * DMODEL * 4;
    bf16* h2  = (bf16*)(ws + off); off += SZ;
    bf16* hid = (bf16*)(ws + off); off += (size_t)N_TOK * DFF * 2;
    int* counts  = (int*)(ws + off); off += 8 * 4;
    int* cursor  = (int*)(ws + off); off += 8 * 4;
    int* offsets = (int*)(ws + off); off += 8 * 4;
    int* sel     = (int*)(ws + off); off += (size_t)N_TOK * 4;
    int* perm    = (int*)(ws + off); off += (size_t)N_TOK * 4;

    zero_kernel<<<1, 64, 0, stream>>>(counts, 16);  // counts + cursor (contiguous)
    ln1_kernel<<<N_TOK, 256, 0, stream>>>(x, ln1g, ln1b, h1h, h1l);
    qkv_gemm<<<dim3(18, 16), 256, 0, stream>>>(h1h, h1l, Wq, Wk, Wv, qh, ql, kh, kl, vh, vl);
    attn_kernel<<<dim3(16, 24), 256, 0, stream>>>(qh, ql, kh, kl, vh, vl, aoh, aol);
    proj_gemm<<<dim3(6, 16), 256, 0, stream>>>(aoh, aol, Wp, bp, x, x1);
    ln2_gate_kernel<<<N_TOK, 256, 0, stream>>>(x1, ln2g, ln2b, Wg, h2, sel, counts);
    scan_kernel<<<1, 64, 0, stream>>>(counts, offsets);
    scatter_kernel<<<8, 256, 0, stream>>>(sel, offsets, cursor, perm);
    moe1_gemm<<<dim3(24, 16, 8), 256, 0, stream>>>(h2, W1, b1, counts, offsets, perm, hid);
    moe2_gemm<<<dim3(6, 16, 8), 256, 0, stream>>>(hid, W2, b2, counts, offsets, perm, x1, out);
}

// Round 3
// 540.034 us; speedup vs baseline: 1.1813x; 1.1813x over previous
//
#include <hip/hip_runtime.h>
#include <math.h>

typedef __bf16 bf16;
typedef __bf16 bf16x8 __attribute__((ext_vector_type(8)));
typedef float f32x4 __attribute__((ext_vector_type(4)));

#define N_TOK 2048
#define DMODEL 768
#define NHEAD 12
#define TSEQ 1024
#define NEXP 8
#define DFF 3072

__device__ inline f32x4 mfma16(bf16x8 a, bf16x8 b, f32x4 c) {
    return __builtin_amdgcn_mfma_f32_16x16x32_bf16(a, b, c, 0, 0, 0);
}

__device__ inline f32x4 zero4() { f32x4 z = {0.f, 0.f, 0.f, 0.f}; return z; }

// ---------------- block reduction (256 threads = 4 waves) ----------------
__device__ inline float block_sum(float v, float* red, int tid) {
#pragma unroll
    for (int off = 32; off > 0; off >>= 1) v += __shfl_down(v, off, 64);
    __syncthreads();
    if ((tid & 63) == 0) red[tid >> 6] = v;
    __syncthreads();
    return red[0] + red[1] + red[2] + red[3];
}

// ---------------- LN1: x -> bf16 hi/lo pair ----------------
__global__ __launch_bounds__(256) void ln1_kernel(const float* __restrict__ x,
        const float* __restrict__ g, const float* __restrict__ b,
        bf16* __restrict__ hh, bf16* __restrict__ hl) {
    __shared__ float red[4];
    int row = blockIdx.x, tid = threadIdx.x;
    const float* xr = x + (size_t)row * DMODEL;
    float v[3];
#pragma unroll
    for (int i = 0; i < 3; i++) v[i] = xr[tid + i * 256];
    float s = block_sum(v[0] + v[1] + v[2], red, tid);
    float mu = s * (1.f / DMODEL);
    float q = 0.f;
#pragma unroll
    for (int i = 0; i < 3; i++) { float d = v[i] - mu; q += d * d; }
    q = block_sum(q, red, tid);
    float rstd = 1.0f / sqrtf(q * (1.f / DMODEL) + 1e-5f);
#pragma unroll
    for (int i = 0; i < 3; i++) {
        int d = tid + i * 256;
        float val = (v[i] - mu) * rstd * g[d] + b[d];
        bf16 hi = (bf16)val;
        hh[(size_t)row * DMODEL + d] = hi;
        hl[(size_t)row * DMODEL + d] = (bf16)(val - (float)hi);
    }
}

// ---------------- shared GEMM pieces ----------------
// LDS tiles: A [128 rows][32 k] stride 40, Bt [128 cols][32 k] stride 40.
// MFMA 16x16x32: A-frag lane reads A[m=lane&15][k=quad*8+j];
// B-frag lane reads Bt[n=lane&15][k=quad*8+j]; C/D: col=lane&15,row=quad*4+reg.
__device__ inline void gemm_step3(const bf16* lah, const bf16* lal,
                                  const bf16* lbh, const bf16* lbl,
                                  int wm, int wn, int row16, int quad,
                                  f32x4 acc[4][4]) {
    bf16x8 ah[4], al[4], bh[4], bl[4];
#pragma unroll
    for (int i = 0; i < 4; i++) {
        int ro = (wm * 64 + i * 16 + row16) * 40 + quad * 8;
        ah[i] = *(const bf16x8*)&lah[ro];
        al[i] = *(const bf16x8*)&lal[ro];
    }
#pragma unroll
    for (int i = 0; i < 4; i++) {
        int ro = (wn * 64 + i * 16 + row16) * 40 + quad * 8;
        bh[i] = *(const bf16x8*)&lbh[ro];
        bl[i] = *(const bf16x8*)&lbl[ro];
    }
#pragma unroll
    for (int mi = 0; mi < 4; mi++)
#pragma unroll
        for (int ni = 0; ni < 4; ni++) {
            acc[mi][ni] = mfma16(ah[mi], bh[ni], acc[mi][ni]);
            acc[mi][ni] = mfma16(ah[mi], bl[ni], acc[mi][ni]);
            acc[mi][ni] = mfma16(al[mi], bh[ni], acc[mi][ni]);
        }
}

__device__ inline void gemm_step1(const bf16* la, const bf16* lb, int wm, int wn,
                                  int row16, int quad, f32x4 acc[4][4]) {
    bf16x8 af[4], bfr[4];
#pragma unroll
    for (int i = 0; i < 4; i++)
        af[i] = *(const bf16x8*)&la[(wm * 64 + i * 16 + row16) * 40 + quad * 8];
#pragma unroll
    for (int i = 0; i < 4; i++)
        bfr[i] = *(const bf16x8*)&lb[(wn * 64 + i * 16 + row16) * 40 + quad * 8];
#pragma unroll
    for (int mi = 0; mi < 4; mi++)
#pragma unroll
        for (int ni = 0; ni < 4; ni++)
            acc[mi][ni] = mfma16(af[mi], bfr[ni], acc[mi][ni]);
}

#define TILE_E (128 * 40)

// ---------------- QKV GEMM (split bf16x3, prefetched): -> q/k/v hi/lo ----------------
__global__ __launch_bounds__(256) void qkv_gemm(const bf16* __restrict__ hA_h,
        const bf16* __restrict__ hA_l,
        const float* __restrict__ Wq, const float* __restrict__ Wk,
        const float* __restrict__ Wv,
        bf16* __restrict__ qh, bf16* __restrict__ ql,
        bf16* __restrict__ kh, bf16* __restrict__ kl,
        bf16* __restrict__ vh, bf16* __restrict__ vl) {
    __shared__ alignas(16) bf16 lah[2 * TILE_E];
    __shared__ alignas(16) bf16 lal[2 * TILE_E];
    __shared__ alignas(16) bf16 lbh[2 * TILE_E];
    __shared__ alignas(16) bf16 lbl[2 * TILE_E];
    int tid = threadIdx.x;
    int m0 = blockIdx.y * 128;
    int nt = blockIdx.x;
    int sel = nt / 6;
    int n0 = (nt % 6) * 128;
    const float* W = (sel == 0) ? Wq : (sel == 1) ? Wk : Wv;
    bf16* obh = (sel == 0) ? qh : (sel == 1) ? kh : vh;
    bf16* obl = (sel == 0) ? ql : (sel == 1) ? kl : vl;
    int lane = tid & 63, w = tid >> 6, row16 = lane & 15, quad = lane >> 4;
    int wm = w >> 1, wn = w & 1;
    int r_a = tid >> 2, c_a = (tid & 3) << 3;
    int nW = tid & 127, kbase = tid >> 7;         // W: n fixed, k = kbase+2i
    size_t wcol = (size_t)((n0 + nW) >> 6) * DMODEL * 64 + ((n0 + nW) & 63);
    f32x4 acc[4][4];
#pragma unroll
    for (int mi = 0; mi < 4; mi++)
#pragma unroll
        for (int ni = 0; ni < 4; ni++) acc[mi][ni] = zero4();
    const bf16* Ah = hA_h + (size_t)m0 * DMODEL;
    const bf16* Al = hA_l + (size_t)m0 * DMODEL;

    bf16x8 rAh0, rAh1, rAl0, rAl1;
    float wv[16];
    // preload slab 0
    rAh0 = *(const bf16x8*)&Ah[(size_t)r_a * DMODEL + c_a];
    rAh1 = *(const bf16x8*)&Ah[(size_t)(r_a + 64) * DMODEL + c_a];
    rAl0 = *(const bf16x8*)&Al[(size_t)r_a * DMODEL + c_a];
    rAl1 = *(const bf16x8*)&Al[(size_t)(r_a + 64) * DMODEL + c_a];
#pragma unroll
    for (int i = 0; i < 16; i++) wv[i] = W[wcol + (size_t)(kbase + 2 * i) * 64];
    // store slab 0
    *(bf16x8*)&lah[r_a * 40 + c_a] = rAh0;
    *(bf16x8*)&lah[(r_a + 64) * 40 + c_a] = rAh1;
    *(bf16x8*)&lal[r_a * 40 + c_a] = rAl0;
    *(bf16x8*)&lal[(r_a + 64) * 40 + c_a] = rAl1;
#pragma unroll
    for (int i = 0; i < 16; i++) {
        bf16 hi = (bf16)wv[i];
        lbh[nW * 40 + kbase + 2 * i] = hi;
        lbl[nW * 40 + kbase + 2 * i] = (bf16)(wv[i] - (float)hi);
    }
    const int nk = DMODEL / 32;
    for (int ki = 0; ki < nk; ki++) {
        __syncthreads();
        int cur = (ki & 1) * TILE_E, nxt = ((ki + 1) & 1) * TILE_E;
        if (ki + 1 < nk) {
            int k0 = (ki + 1) * 32;
            rAh0 = *(const bf16x8*)&Ah[(size_t)r_a * DMODEL + k0 + c_a];
            rAh1 = *(const bf16x8*)&Ah[(size_t)(r_a + 64) * DMODEL + k0 + c_a];
            rAl0 = *(const bf16x8*)&Al[(size_t)r_a * DMODEL + k0 + c_a];
            rAl1 = *(const bf16x8*)&Al[(size_t)(r_a + 64) * DMODEL + k0 + c_a];
#pragma unroll
            for (int i = 0; i < 16; i++)
                wv[i] = W[wcol + (size_t)(k0 + kbase + 2 * i) * 64];
        }
        gemm_step3(lah + cur, lal + cur, lbh + cur, lbl + cur, wm, wn, row16, quad, acc);
        if (ki + 1 < nk) {
            *(bf16x8*)&lah[nxt + r_a * 40 + c_a] = rAh0;
            *(bf16x8*)&lah[nxt + (r_a + 64) * 40 + c_a] = rAh1;
            *(bf16x8*)&lal[nxt + r_a * 40 + c_a] = rAl0;
            *(bf16x8*)&lal[nxt + (r_a + 64) * 40 + c_a] = rAl1;
#pragma unroll
            for (int i = 0; i < 16; i++) {
                bf16 hi = (bf16)wv[i];
                lbh[nxt + nW * 40 + kbase + 2 * i] = hi;
                lbl[nxt + nW * 40 + kbase + 2 * i] = (bf16)(wv[i] - (float)hi);
            }
        }
    }
#pragma unroll
    for (int mi = 0; mi < 4; mi++) {
        int rowl = wm * 64 + mi * 16 + quad * 4;
#pragma unroll
        for (int ni = 0; ni < 4; ni++) {
            int col = n0 + wn * 64 + ni * 16 + row16;
            int hhd = col >> 6, s = col & 63;
#pragma unroll
            for (int r = 0; r < 4; r++) {
                int gm = m0 + rowl + r;
                int bb = gm >> 10, t = gm & 1023;
                size_t oi = (((size_t)bb * NHEAD + hhd) * TSEQ + t) * 64 + s;
                float val = acc[mi][ni][r];
                bf16 hi = (bf16)val;
                obh[oi] = hi;
                obl[oi] = (bf16)(val - (float)hi);
            }
        }
    }
}

// ---------------- flash attention (split bf16x3), causal ----------------
__global__ __launch_bounds__(256) void attn_kernel(const bf16* __restrict__ qhb,
        const bf16* __restrict__ qlb, const bf16* __restrict__ khb,
        const bf16* __restrict__ klb, const bf16* __restrict__ vhb,
        const bf16* __restrict__ vlb, bf16* __restrict__ aoh,
        bf16* __restrict__ aol) {
    __shared__ alignas(16) bf16 kt_h[64 * 72];
    __shared__ alignas(16) bf16 kt_l[64 * 72];
    __shared__ alignas(16) bf16 vt_h[64 * 72];
    __shared__ alignas(16) bf16 vt_l[64 * 72];
    __shared__ alignas(16) bf16 p_h[4][16 * 72];
    __shared__ alignas(16) bf16 p_l[4][16 * 72];
    int qt = blockIdx.x, bh = blockIdx.y;
    int b = bh / NHEAD, hh = bh % NHEAD;
    int tid = threadIdx.x, lane = tid & 63, w = tid >> 6;
    int row16 = lane & 15, quad = lane >> 4;
    const bf16* qph = qhb + (size_t)bh * TSEQ * 64;
    const bf16* qpl = qlb + (size_t)bh * TSEQ * 64;
    const bf16* kph = khb + (size_t)bh * TSEQ * 64;
    const bf16* kpl = klb + (size_t)bh * TSEQ * 64;
    const bf16* vph = vhb + (size_t)bh * TSEQ * 64;
    const bf16* vpl = vlb + (size_t)bh * TSEQ * 64;
    int qrow = qt * 64 + w * 16 + row16;
    bf16x8 aq_h[2], aq_l[2];
#pragma unroll
    for (int kk = 0; kk < 2; kk++) {
        aq_h[kk] = *(const bf16x8*)&qph[(size_t)qrow * 64 + kk * 32 + quad * 8];
        aq_l[kk] = *(const bf16x8*)&qpl[(size_t)qrow * 64 + kk * 32 + quad * 8];
    }
    f32x4 o[4];
    float m_i[4], l_i[4];
#pragma unroll
    for (int i = 0; i < 4; i++) { o[i] = zero4(); m_i[i] = -INFINITY; l_i[i] = 0.f; }
    const float sc = 0.03608439182435161f;  // 768^-0.5
    for (int kt = 0; kt <= qt; kt++) {
        __syncthreads();
#pragma unroll
        for (int i = 0; i < 2; i++) {
            int chunk = tid + i * 256;
            int r = chunk >> 3, c = (chunk & 7) << 3;
            size_t gi = (size_t)(kt * 64 + r) * 64 + c;
            *(bf16x8*)&kt_h[r * 72 + c] = *(const bf16x8*)&kph[gi];
            *(bf16x8*)&kt_l[r * 72 + c] = *(const bf16x8*)&kpl[gi];
        }
#pragma unroll
        for (int i = 0; i < 16; i++) {
            int idx = tid + (i << 8);
            int tk = idx >> 6, s = idx & 63;
            size_t gi = (size_t)(kt * 64 + tk) * 64 + s;
            vt_h[s * 72 + tk] = vph[gi];
            vt_l[s * 72 + tk] = vpl[gi];
        }
        __syncthreads();
        f32x4 sacc[4];
#pragma unroll
        for (int ni = 0; ni < 4; ni++) {
            sacc[ni] = zero4();
#pragma unroll
            for (int kk = 0; kk < 2; kk++) {
                int ro = (ni * 16 + row16) * 72 + kk * 32 + quad * 8;
                bf16x8 bk_h = *(const bf16x8*)&kt_h[ro];
                bf16x8 bk_l = *(const bf16x8*)&kt_l[ro];
                sacc[ni] = mfma16(aq_h[kk], bk_h, sacc[ni]);
                sacc[ni] = mfma16(aq_h[kk], bk_l, sacc[ni]);
                sacc[ni] = mfma16(aq_l[kk], bk_h, sacc[ni]);
            }
        }
        float mrow[4];
#pragma unroll
        for (int r = 0; r < 4; r++) mrow[r] = -INFINITY;
        int tq_b = qt * 64 + w * 16 + quad * 4;
#pragma unroll
        for (int ni = 0; ni < 4; ni++) {
            int tkg = kt * 64 + ni * 16 + row16;
#pragma unroll
            for (int r = 0; r < 4; r++) {
                float sv = sacc[ni][r] * sc;
                if (tkg > tq_b + r) sv = -INFINITY;
                sacc[ni][r] = sv;
                mrow[r] = fmaxf(mrow[r], sv);
            }
        }
#pragma unroll
        for (int r = 0; r < 4; r++) {
#pragma unroll
            for (int off = 8; off > 0; off >>= 1)
                mrow[r] = fmaxf(mrow[r], __shfl_xor(mrow[r], off, 16));
        }
        float alpha[4], rsum[4];
#pragma unroll
        for (int r = 0; r < 4; r++) {
            float nm = fmaxf(m_i[r], mrow[r]);
            alpha[r] = __expf(m_i[r] - nm);
            m_i[r] = nm;
            rsum[r] = 0.f;
        }
#pragma unroll
        for (int ni = 0; ni < 4; ni++)
#pragma unroll
            for (int r = 0; r < 4; r++) {
                float p = __expf(sacc[ni][r] - m_i[r]);
                sacc[ni][r] = p;
                rsum[r] += p;
            }
#pragma unroll
        for (int r = 0; r < 4; r++) {
#pragma unroll
            for (int off = 8; off > 0; off >>= 1)
                rsum[r] += __shfl_xor(rsum[r], off, 16);
            l_i[r] = l_i[r] * alpha[r] + rsum[r];
        }
#pragma unroll
        for (int ni = 0; ni < 4; ni++)
#pragma unroll
            for (int r = 0; r < 4; r++) o[ni][r] *= alpha[r];
#pragma unroll
        for (int ni = 0; ni < 4; ni++)
#pragma unroll
            for (int r = 0; r < 4; r++) {
                float p = sacc[ni][r];
                bf16 hi = (bf16)p;
                int po = (quad * 4 + r) * 72 + ni * 16 + row16;
                p_h[w][po] = hi;
                p_l[w][po] = (bf16)(p - (float)hi);
            }
        __syncthreads();
        bf16x8 ap_h[2], ap_l[2];
#pragma unroll
        for (int kk = 0; kk < 2; kk++) {
            ap_h[kk] = *(const bf16x8*)&p_h[w][row16 * 72 + kk * 32 + quad * 8];
            ap_l[kk] = *(const bf16x8*)&p_l[w][row16 * 72 + kk * 32 + quad * 8];
        }
#pragma unroll
        for (int ni = 0; ni < 4; ni++)
#pragma unroll
            for (int kk = 0; kk < 2; kk++) {
                int ro = (ni * 16 + row16) * 72 + kk * 32 + quad * 8;
                bf16x8 bv_h = *(const bf16x8*)&vt_h[ro];
                bf16x8 bv_l = *(const bf16x8*)&vt_l[ro];
                o[ni] = mfma16(ap_h[kk], bv_h, o[ni]);
                o[ni] = mfma16(ap_h[kk], bv_l, o[ni]);
                o[ni] = mfma16(ap_l[kk], bv_h, o[ni]);
            }
    }
    int t = qt * 64 + w * 16 + quad * 4;
#pragma unroll
    for (int ni = 0; ni < 4; ni++) {
        int col = hh * 64 + ni * 16 + row16;
#pragma unroll
        for (int r = 0; r < 4; r++) {
            float val = o[ni][r] / l_i[r];
            size_t n = (size_t)b * TSEQ + t + r;
            bf16 hi = (bf16)val;
            aoh[n * DMODEL + col] = hi;
            aol[n * DMODEL + col] = (bf16)(val - (float)hi);
        }
    }
}

// ---------------- proj GEMM (split bf16x3, prefetched) ----------------
__global__ __launch_bounds__(256) void proj_gemm(const bf16* __restrict__ aInH,
        const bf16* __restrict__ aInL,
        const float* __restrict__ Wp, const float* __restrict__ bp,
        const float* __restrict__ x, float* __restrict__ x1) {
    __shared__ alignas(16) bf16 lah[2 * TILE_E];
    __shared__ alignas(16) bf16 lal[2 * TILE_E];
    __shared__ alignas(16) bf16 lbh[2 * TILE_E];
    __shared__ alignas(16) bf16 lbl[2 * TILE_E];
    int tid = threadIdx.x;
    int m0 = blockIdx.y * 128, n0 = blockIdx.x * 128;
    int lane = tid & 63, w = tid >> 6, row16 = lane & 15, quad = lane >> 4;
    int wm = w >> 1, wn = w & 1;
    int r_a = tid >> 2, c_a = (tid & 3) << 3;
    int nW = tid & 127, kbase = tid >> 7;
    f32x4 acc[4][4];
#pragma unroll
    for (int mi = 0; mi < 4; mi++)
#pragma unroll
        for (int ni = 0; ni < 4; ni++) acc[mi][ni] = zero4();
    const bf16* Ah = aInH + (size_t)m0 * DMODEL;
    const bf16* Al = aInL + (size_t)m0 * DMODEL;
    bf16x8 rAh0, rAh1, rAl0, rAl1;
    float wv[16];
    rAh0 = *(const bf16x8*)&Ah[(size_t)r_a * DMODEL + c_a];
    rAh1 = *(const bf16x8*)&Ah[(size_t)(r_a + 64) * DMODEL + c_a];
    rAl0 = *(const bf16x8*)&Al[(size_t)r_a * DMODEL + c_a];
    rAl1 = *(const bf16x8*)&Al[(size_t)(r_a + 64) * DMODEL + c_a];
#pragma unroll
    for (int i = 0; i < 16; i++)
        wv[i] = Wp[(size_t)(kbase + 2 * i) * DMODEL + n0 + nW];
    *(bf16x8*)&lah[r_a * 40 + c_a] = rAh0;
    *(bf16x8*)&lah[(r_a + 64) * 40 + c_a] = rAh1;
    *(bf16x8*)&lal[r_a * 40 + c_a] = rAl0;
    *(bf16x8*)&lal[(r_a + 64) * 40 + c_a] = rAl1;
#pragma unroll
    for (int i = 0; i < 16; i++) {
        bf16 hi = (bf16)wv[i];
        lbh[nW * 40 + kbase + 2 * i] = hi;
        lbl[nW * 40 + kbase + 2 * i] = (bf16)(wv[i] - (float)hi);
    }
    const int nk = DMODEL / 32;
    for (int ki = 0; ki < nk; ki++) {
        __syncthreads();
        int cur = (ki & 1) * TILE_E, nxt = ((ki + 1) & 1) * TILE_E;
        if (ki + 1 < nk) {
            int k0 = (ki + 1) * 32;
            rAh0 = *(const bf16x8*)&Ah[(size_t)r_a * DMODEL + k0 + c_a];
            rAh1 = *(const bf16x8*)&Ah[(size_t)(r_a + 64) * DMODEL + k0 + c_a];
            rAl0 = *(const bf16x8*)&Al[(size_t)r_a * DMODEL + k0 + c_a];
            rAl1 = *(const bf16x8*)&Al[(size_t)(r_a + 64) * DMODEL + k0 + c_a];
#pragma unroll
            for (int i = 0; i < 16; i++)
                wv[i] = Wp[(size_t)(k0 + kbase + 2 * i) * DMODEL + n0 + nW];
        }
        gemm_step3(lah + cur, lal + cur, lbh + cur, lbl + cur, wm, wn, row16, quad, acc);
        if (ki + 1 < nk) {
            *(bf16x8*)&lah[nxt + r_a * 40 + c_a] = rAh0;
            *(bf16x8*)&lah[nxt + (r_a + 64) * 40 + c_a] = rAh1;
            *(bf16x8*)&lal[nxt + r_a * 40 + c_a] = rAl0;
            *(bf16x8*)&lal[nxt + (r_a + 64) * 40 + c_a] = rAl1;
#pragma unroll
            for (int i = 0; i < 16; i++) {
                bf16 hi = (bf16)wv[i];
                lbh[nxt + nW * 40 + kbase + 2 * i] = hi;
                lbl[nxt + nW * 40 + kbase + 2 * i] = (bf16)(wv[i] - (float)hi);
            }
        }
    }
#pragma unroll
    for (int mi = 0; mi < 4; mi++) {
        int rowl = wm * 64 + mi * 16 + quad * 4;
#pragma unroll
        for (int ni = 0; ni < 4; ni++) {
            int col = n0 + wn * 64 + ni * 16 + row16;
#pragma unroll
            for (int r = 0; r < 4; r++) {
                int gm = m0 + rowl + r;
                x1[(size_t)gm * DMODEL + col] =
                    acc[mi][ni][r] + bp[col] + x[(size_t)gm * DMODEL + col];
            }
        }
    }
}

// ---------------- LN2 + gate argmax + expert counting ----------------
__global__ __launch_bounds__(256) void ln2_gate_kernel(const float* __restrict__ x1,
        const float* __restrict__ g, const float* __restrict__ b,
        const float* __restrict__ Wg, bf16* __restrict__ h2,
        int* __restrict__ sel, int* __restrict__ counts) {
    __shared__ float red[4];
    __shared__ float glog[8];
    int row = blockIdx.x, tid = threadIdx.x;
    if (tid < 8) glog[tid] = 0.f;
    const float* xr = x1 + (size_t)row * DMODEL;
    float v[3];
#pragma unroll
    for (int i = 0; i < 3; i++) v[i] = xr[tid + i * 256];
    float s = block_sum(v[0] + v[1] + v[2], red, tid);
    float mu = s * (1.f / DMODEL);
    float qv = 0.f;
#pragma unroll
    for (int i = 0; i < 3; i++) { float d = v[i] - mu; qv += d * d; }
    qv = block_sum(qv, red, tid);
    float rstd = 1.0f / sqrtf(qv * (1.f / DMODEL) + 1e-5f);
    float ga[8];
#pragma unroll
    for (int e = 0; e < 8; e++) ga[e] = 0.f;
#pragma unroll
    for (int i = 0; i < 3; i++) {
        int d = tid + i * 256;
        float hv = (v[i] - mu) * rstd * g[d] + b[d];
        h2[(size_t)row * DMODEL + d] = (bf16)hv;
        const float* wgr = Wg + (size_t)d * NEXP;
#pragma unroll
        for (int e = 0; e < 8; e++) ga[e] += hv * wgr[e];
    }
#pragma unroll
    for (int e = 0; e < 8; e++)
#pragma unroll
        for (int off = 32; off > 0; off >>= 1) ga[e] += __shfl_down(ga[e], off, 64);
    if ((tid & 63) == 0)
#pragma unroll
        for (int e = 0; e < 8; e++) atomicAdd(&glog[e], ga[e]);
    __syncthreads();
    if (tid == 0) {
        float best = glog[0];
        int bi = 0;
#pragma unroll
        for (int e = 1; e < 8; e++)
            if (glog[e] > best) { best = glog[e]; bi = e; }
        sel[row] = bi;
        atomicAdd(&counts[bi], 1);
    }
}

// ---------------- routing helpers ----------------
__global__ void zero_kernel(int* __restrict__ p, int n) {
    int i = blockIdx.x * blockDim.x + threadIdx.x;
    if (i < n) p[i] = 0;
}
__global__ void zero_out_kernel(float* __restrict__ p) {
    int i = blockIdx.x * blockDim.x + threadIdx.x;
    f32x4 z = zero4();
    *(f32x4*)&p[i * 4] = z;
}
__global__ void scan_kernel(const int* __restrict__ counts, int* __restrict__ offsets) {
    if (threadIdx.x == 0) {
        int o = 0;
        for (int e = 0; e < NEXP; e++) { offsets[e] = o; o += counts[e]; }
    }
}
__global__ void scatter_kernel(const int* __restrict__ sel, const int* __restrict__ offsets,
                               int* __restrict__ cursor, int* __restrict__ perm) {
    int n = blockIdx.x * blockDim.x + threadIdx.x;
    if (n >= N_TOK) return;
    int e = sel[n];
    int pos = atomicAdd(&cursor[e], 1);
    perm[offsets[e] + pos] = n;
}

// ---------------- MoE GEMM1 (prefetched): hid = relu(h2[perm] @ W1[e] + b1[e]) ----------------
__global__ __launch_bounds__(256) void moe1_gemm(const bf16* __restrict__ h2,
        const float* __restrict__ W1, const float* __restrict__ b1,
        const int* __restrict__ counts, const int* __restrict__ offsets,
        const int* __restrict__ perm, bf16* __restrict__ hid) {
    int e = blockIdx.z;
    int cnt = counts[e];
    int rt = blockIdx.y;
    if (rt * 128 >= cnt) return;
    int off = offsets[e];
    int n0 = blockIdx.x * 128;
    const float* W = W1 + (size_t)e * DMODEL * DFF;
    __shared__ alignas(16) bf16 la[2 * TILE_E];
    __shared__ alignas(16) bf16 lb[2 * TILE_E];
    int tid = threadIdx.x;
    int lane = tid & 63, w = tid >> 6, row16 = lane & 15, quad = lane >> 4;
    int wm = w >> 1, wn = w & 1;
    int r_a = tid >> 2, c_a = (tid & 3) << 3;
    int nW = tid & 127, kbase = tid >> 7;
    int tok0 = perm[off + min(rt * 128 + r_a, cnt - 1)];
    int tok1 = perm[off + min(rt * 128 + r_a + 64, cnt - 1)];
    const bf16* a0 = h2 + (size_t)tok0 * DMODEL;
    const bf16* a1 = h2 + (size_t)tok1 * DMODEL;
    f32x4 acc[4][4];
#pragma unroll
    for (int mi = 0; mi < 4; mi++)
#pragma unroll
        for (int ni = 0; ni < 4; ni++) acc[mi][ni] = zero4();
    bf16x8 rA0, rA1;
    float wv[16];
    rA0 = *(const bf16x8*)&a0[c_a];
    rA1 = *(const bf16x8*)&a1[c_a];
#pragma unroll
    for (int i = 0; i < 16; i++)
        wv[i] = W[(size_t)(kbase + 2 * i) * DFF + n0 + nW];
    *(bf16x8*)&la[r_a * 40 + c_a] = rA0;
    *(bf16x8*)&la[(r_a + 64) * 40 + c_a] = rA1;
#pragma unroll
    for (int i = 0; i < 16; i++) lb[nW * 40 + kbase + 2 * i] = (bf16)wv[i];
    const int nk = DMODEL / 32;
    for (int ki = 0; ki < nk; ki++) {
        __syncthreads();
        int cur = (ki & 1) * TILE_E, nxt = ((ki + 1) & 1) * TILE_E;
        if (ki + 1 < nk) {
            int k0 = (ki + 1) * 32;
            rA0 = *(const bf16x8*)&a0[k0 + c_a];
            rA1 = *(const bf16x8*)&a1[k0 + c_a];
#pragma unroll
            for (int i = 0; i < 16; i++)
                wv[i] = W[(size_t)(k0 + kbase + 2 * i) * DFF + n0 + nW];
        }
        gemm_step1(la + cur, lb + cur, wm, wn, row16, quad, acc);
        if (ki + 1 < nk) {
            *(bf16x8*)&la[nxt + r_a * 40 + c_a] = rA0;
            *(bf16x8*)&la[nxt + (r_a + 64) * 40 + c_a] = rA1;
#pragma unroll
            for (int i = 0; i < 16; i++) lb[nxt + nW * 40 + kbase + 2 * i] = (bf16)wv[i];
        }
    }
#pragma unroll
    for (int mi = 0; mi < 4; mi++) {
        int rowl = wm * 64 + mi * 16 + quad * 4;
#pragma unroll
        for (int ni = 0; ni < 4; ni++) {
            int col = n0 + wn * 64 + ni * 16 + row16;
#pragma unroll
            for (int r = 0; r < 4; r++) {
                int lr = rowl + r;
                if (rt * 128 + lr < cnt) {
                    float val = acc[mi][ni][r] + b1[(size_t)e * DFF + col];
                    val = fmaxf(val, 0.f);
                    hid[(size_t)(off + rt * 128 + lr) * DFF + col] = (bf16)val;
                }
            }
        }
    }
}

// ---------------- MoE GEMM2 (prefetched, split-K=2, atomic): out += ... ----------------
__global__ __launch_bounds__(256) void moe2_gemm(const bf16* __restrict__ hid,
        const float* __restrict__ W2, const float* __restrict__ b2,
        const int* __restrict__ counts, const int* __restrict__ offsets,
        const int* __restrict__ perm, const float* __restrict__ x1,
        float* __restrict__ out) {
    int ez = blockIdx.z;
    int e = ez >> 1, ks = ez & 1;
    int cnt = counts[e];
    int rt = blockIdx.y;
    if (rt * 128 >= cnt) return;
    int off = offsets[e];
    int n0 = blockIdx.x * 128;
    const float* W = W2 + (size_t)e * DFF * DMODEL;
    __shared__ alignas(16) bf16 la[2 * TILE_E];
    __shared__ alignas(16) bf16 lb[2 * TILE_E];
    int tid = threadIdx.x;
    int lane = tid & 63, w = tid >> 6, row16 = lane & 15, quad = lane >> 4;
    int wm = w >> 1, wn = w & 1;
    int r_a = tid >> 2, c_a = (tid & 3) << 3;
    int nW = tid & 127, kbase = tid >> 7;
    const bf16* a0 = hid + (size_t)min(off + rt * 128 + r_a, N_TOK - 1) * DFF;
    const bf16* a1 = hid + (size_t)min(off + rt * 128 + r_a + 64, N_TOK - 1) * DFF;
    f32x4 acc[4][4];
#pragma unroll
    for (int mi = 0; mi < 4; mi++)
#pragma unroll
        for (int ni = 0; ni < 4; ni++) acc[mi][ni] = zero4();
    const int kst = ks * (DFF / 2);
    bf16x8 rA0, rA1;
    float wv[16];
    rA0 = *(const bf16x8*)&a0[kst + c_a];
    rA1 = *(const bf16x8*)&a1[kst + c_a];
#pragma unroll
    for (int i = 0; i < 16; i++)
        wv[i] = W[(size_t)(kst + kbase + 2 * i) * DMODEL + n0 + nW];
    *(bf16x8*)&la[r_a * 40 + c_a] = rA0;
    *(bf16x8*)&la[(r_a + 64) * 40 + c_a] = rA1;
#pragma unroll
    for (int i = 0; i < 16; i++) lb[nW * 40 + kbase + 2 * i] = (bf16)wv[i];
    const int nk = (DFF / 2) / 32;
    for (int ki = 0; ki < nk; ki++) {
        __syncthreads();
        int cur = (ki & 1) * TILE_E, nxt = ((ki + 1) & 1) * TILE_E;
        if (ki + 1 < nk) {
            int k0 = kst + (ki + 1) * 32;
            rA0 = *(const bf16x8*)&a0[k0 + c_a];
            rA1 = *(const bf16x8*)&a1[k0 + c_a];
#pragma unroll
            for (int i = 0; i < 16; i++)
                wv[i] = W[(size_t)(k0 + kbase + 2 * i) * DMODEL + n0 + nW];
        }
        gemm_step1(la + cur, lb + cur, wm, wn, row16, quad, acc);
        if (ki + 1 < nk) {
            *(bf16x8*)&la[nxt + r_a * 40 + c_a] = rA0;
            *(bf16x8*)&la[nxt + (r_a + 64) * 40 + c_a] = rA1;
#pragma unroll
            for (int i = 0; i < 16; i++) lb[nxt + nW * 40 + kbase + 2 * i] = (bf16)wv[i];
        }
    }
#pragma unroll
    for (int mi = 0; mi < 4; mi++) {
        int rowl = wm * 64 + mi * 16 + quad * 4;
#pragma unroll
        for (int ni = 0; ni < 4; ni++) {
            int col = n0 + wn * 64 + ni * 16 + row16;
#pragma unroll
            for (int r = 0; r < 4; r++) {
                int lr = rowl + r;
                if (rt * 128 + lr < cnt) {
                    int n = perm[off + rt * 128 + lr];
                    float val = acc[mi][ni][r];
                    if (ks == 0)
                        val += b2[(size_t)e * DMODEL + col] + x1[(size_t)n * DMODEL + col];
                    atomicAdd(&out[(size_t)n * DMODEL + col], val);
                }
            }
        }
    }
}

// ---------------- launch ----------------
extern "C" void kernel_launch(void* const* d_in, const int* in_sizes, int n_in,
                              void* d_out, int out_size, void* d_ws, size_t ws_size,
                              hipStream_t stream) {
    const float* x    = (const float*)d_in[0];
    const float* ln1g = (const float*)d_in[1];
    const float* ln1b = (const float*)d_in[2];
    const float* ln2g = (const float*)d_in[3];
    const float* ln2b = (const float*)d_in[4];
    const float* Wq   = (const float*)d_in[5];
    const float* Wk   = (const float*)d_in[6];
    const float* Wv   = (const float*)d_in[7];
    const float* Wp   = (const float*)d_in[8];
    const float* bp   = (const float*)d_in[9];
    const float* Wg   = (const float*)d_in[10];
    const float* W1   = (const float*)d_in[11];
    const float* b1   = (const float*)d_in[12];
    const float* W2   = (const float*)d_in[13];
    const float* b2   = (const float*)d_in[14];
    float* out = (float*)d_out;

    char* ws = (char*)d_ws;
    size_t off = 0;
    const size_t SZ = (size_t)N_TOK * DMODEL * 2;
    bf16* h1h = (bf16*)(ws + off); off += SZ;
    bf16* h1l = (bf16*)(ws + off); off += SZ;
    bf16* qh  = (bf16*)(ws + off); off += SZ;
    bf16* ql  = (bf16*)(ws + off); off += SZ;
    bf16* kh  = (bf16*)(ws + off); off += SZ;
    bf16* kl  = (bf16*)(ws + off); off += SZ;
    bf16* vh  = (bf16*)(ws + off); off += SZ;
    bf16* vl  = (bf16*)(ws + off); off += SZ;
    bf16* aoh = (bf16*)(ws + off); off += SZ;
    bf16* aol = (bf16*)(ws + off); off += SZ;
    float* x1 = (float*)(ws + off); off += (size_t)N_TOK * DMODEL * 4;
    bf16* h2  = (bf16*)(ws + off); off += SZ;
    bf16* hid = (bf16*)(ws + off); off += (size_t)N_TOK * DFF * 2;
    int* counts  = (int*)(ws + off); off += 8 * 4;
    int* cursor  = (int*)(ws + off); off += 8 * 4;
    int* offsets = (int*)(ws + off); off += 8 * 4;
    int* sel     = (int*)(ws + off); off += (size_t)N_TOK * 4;
    int* perm    = (int*)(ws + off); off += (size_t)N_TOK * 4;

    zero_kernel<<<1, 64, 0, stream>>>(counts, 16);
    zero_out_kernel<<<N_TOK * DMODEL / 4 / 256, 256, 0, stream>>>(out);
    ln1_kernel<<<N_TOK, 256, 0, stream>>>(x, ln1g, ln1b, h1h, h1l);
    qkv_gemm<<<dim3(18, 16), 256, 0, stream>>>(h1h, h1l, Wq, Wk, Wv, qh, ql, kh, kl, vh, vl);
    attn_kernel<<<dim3(16, 24), 256, 0, stream>>>(qh, ql, kh, kl, vh, vl, aoh, aol);
    proj_gemm<<<dim3(6, 16), 256, 0, stream>>>(aoh, aol, Wp, bp, x, x1);
    ln2_gate_kernel<<<N_TOK, 256, 0, stream>>>(x1, ln2g, ln2b, Wg, h2, sel, counts);
    scan_kernel<<<1, 64, 0, stream>>>(counts, offsets);
    scatter_kernel<<<8, 256, 0, stream>>>(sel, offsets, cursor, perm);
    moe1_gemm<<<dim3(24, 16, 8), 256, 0, stream>>>(h2, W1, b1, counts, offsets, perm, hid);
    moe2_gemm<<<dim3(6, 16, 16), 256, 0, stream>>>(hid, W2, b2, counts, offsets, perm, x1, out);
}

// Round 4
// 511.830 us; speedup vs baseline: 1.2463x; 1.0551x over previous
//
#include <hip/hip_runtime.h>
#include <math.h>

typedef __bf16 bf16;
typedef __bf16 bf16x4 __attribute__((ext_vector_type(4)));
typedef __bf16 bf16x8 __attribute__((ext_vector_type(8)));
typedef float f32x4 __attribute__((ext_vector_type(4)));

#define N_TOK 2048
#define DMODEL 768
#define NHEAD 12
#define TSEQ 1024
#define NEXP 8
#define DFF 3072

__device__ inline f32x4 mfma16(bf16x8 a, bf16x8 b, f32x4 c) {
    return __builtin_amdgcn_mfma_f32_16x16x32_bf16(a, b, c, 0, 0, 0);
}

__device__ inline f32x4 zero4() { f32x4 z = {0.f, 0.f, 0.f, 0.f}; return z; }

// ---------------- block reduction (256 threads = 4 waves) ----------------
__device__ inline float block_sum(float v, float* red, int tid) {
#pragma unroll
    for (int off = 32; off > 0; off >>= 1) v += __shfl_down(v, off, 64);
    __syncthreads();
    if ((tid & 63) == 0) red[tid >> 6] = v;
    __syncthreads();
    return red[0] + red[1] + red[2] + red[3];
}

// ---------------- LN1 (+ zero counts/cursor/out): x -> bf16 hi/lo ----------------
__global__ __launch_bounds__(256) void ln1_kernel(const float* __restrict__ x,
        const float* __restrict__ g, const float* __restrict__ b,
        bf16* __restrict__ hh, bf16* __restrict__ hl,
        int* __restrict__ cz, float* __restrict__ outz) {
    __shared__ float red[4];
    int row = blockIdx.x, tid = threadIdx.x;
    if (row == 0 && tid < 16) cz[tid] = 0;
    // zero this row of out (for moe2 atomics)
#pragma unroll
    for (int i = 0; i < 3; i++) outz[(size_t)row * DMODEL + tid + i * 256] = 0.f;
    const float* xr = x + (size_t)row * DMODEL;
    float v[3];
#pragma unroll
    for (int i = 0; i < 3; i++) v[i] = xr[tid + i * 256];
    float s = block_sum(v[0] + v[1] + v[2], red, tid);
    float mu = s * (1.f / DMODEL);
    float q = 0.f;
#pragma unroll
    for (int i = 0; i < 3; i++) { float d = v[i] - mu; q += d * d; }
    q = block_sum(q, red, tid);
    float rstd = 1.0f / sqrtf(q * (1.f / DMODEL) + 1e-5f);
#pragma unroll
    for (int i = 0; i < 3; i++) {
        int d = tid + i * 256;
        float val = (v[i] - mu) * rstd * g[d] + b[d];
        bf16 hi = (bf16)val;
        hh[(size_t)row * DMODEL + d] = hi;
        hl[(size_t)row * DMODEL + d] = (bf16)(val - (float)hi);
    }
}

// ---------------- shared GEMM pieces ----------------
__device__ inline void gemm_step3(const bf16* lah, const bf16* lal,
                                  const bf16* lbh, const bf16* lbl,
                                  int wm, int wn, int row16, int quad,
                                  f32x4 acc[4][4]) {
    bf16x8 ah[4], al[4], bh[4], bl[4];
#pragma unroll
    for (int i = 0; i < 4; i++) {
        int ro = (wm * 64 + i * 16 + row16) * 40 + quad * 8;
        ah[i] = *(const bf16x8*)&lah[ro];
        al[i] = *(const bf16x8*)&lal[ro];
    }
#pragma unroll
    for (int i = 0; i < 4; i++) {
        int ro = (wn * 64 + i * 16 + row16) * 40 + quad * 8;
        bh[i] = *(const bf16x8*)&lbh[ro];
        bl[i] = *(const bf16x8*)&lbl[ro];
    }
#pragma unroll
    for (int mi = 0; mi < 4; mi++)
#pragma unroll
        for (int ni = 0; ni < 4; ni++) {
            acc[mi][ni] = mfma16(ah[mi], bh[ni], acc[mi][ni]);
            acc[mi][ni] = mfma16(ah[mi], bl[ni], acc[mi][ni]);
            acc[mi][ni] = mfma16(al[mi], bh[ni], acc[mi][ni]);
        }
}

__device__ inline void gemm_step1(const bf16* la, const bf16* lb, int wm, int wn,
                                  int row16, int quad, f32x4 acc[4][4]) {
    bf16x8 af[4], bfr[4];
#pragma unroll
    for (int i = 0; i < 4; i++)
        af[i] = *(const bf16x8*)&la[(wm * 64 + i * 16 + row16) * 40 + quad * 8];
#pragma unroll
    for (int i = 0; i < 4; i++)
        bfr[i] = *(const bf16x8*)&lb[(wn * 64 + i * 16 + row16) * 40 + quad * 8];
#pragma unroll
    for (int mi = 0; mi < 4; mi++)
#pragma unroll
        for (int ni = 0; ni < 4; ni++)
            acc[mi][ni] = mfma16(af[mi], bfr[ni], acc[mi][ni]);
}

#define TILE_E (128 * 40)

// write 16 k-consecutive converted values as 4 x b64 (conflict /4 vs b16 scatter)
__device__ inline void wstore_hilo(bf16* lbh, bf16* lbl, int base, const float* wv) {
#pragma unroll
    for (int gq = 0; gq < 4; gq++) {
        bf16x4 ph, pl;
#pragma unroll
        for (int j = 0; j < 4; j++) {
            float v = wv[gq * 4 + j];
            bf16 hi = (bf16)v;
            ph[j] = hi;
            pl[j] = (bf16)(v - (float)hi);
        }
        *(bf16x4*)&lbh[base + gq * 4] = ph;
        *(bf16x4*)&lbl[base + gq * 4] = pl;
    }
}
__device__ inline void wstore1(bf16* lb, int base, const float* wv) {
#pragma unroll
    for (int gq = 0; gq < 4; gq++) {
        bf16x4 p;
#pragma unroll
        for (int j = 0; j < 4; j++) p[j] = (bf16)wv[gq * 4 + j];
        *(bf16x4*)&lb[base + gq * 4] = p;
    }
}

// ---------------- QKV GEMM (split bf16x3, prefetched) ----------------
__global__ __launch_bounds__(256) void qkv_gemm(const bf16* __restrict__ hA_h,
        const bf16* __restrict__ hA_l,
        const float* __restrict__ Wq, const float* __restrict__ Wk,
        const float* __restrict__ Wv,
        bf16* __restrict__ qh, bf16* __restrict__ ql,
        bf16* __restrict__ kh, bf16* __restrict__ kl,
        bf16* __restrict__ vh, bf16* __restrict__ vl) {
    __shared__ alignas(16) bf16 lah[2 * TILE_E];
    __shared__ alignas(16) bf16 lal[2 * TILE_E];
    __shared__ alignas(16) bf16 lbh[2 * TILE_E];
    __shared__ alignas(16) bf16 lbl[2 * TILE_E];
    int tid = threadIdx.x;
    int m0 = blockIdx.y * 128;
    int nt = blockIdx.x;
    int sel = nt / 6;
    int n0 = (nt % 6) * 128;
    const float* W = (sel == 0) ? Wq : (sel == 1) ? Wk : Wv;
    bf16* obh = (sel == 0) ? qh : (sel == 1) ? kh : vh;
    bf16* obl = (sel == 0) ? ql : (sel == 1) ? kl : vl;
    int lane = tid & 63, w = tid >> 6, row16 = lane & 15, quad = lane >> 4;
    int wm = w >> 1, wn = w & 1;
    int r_a = tid >> 2, c_a = (tid & 3) << 3;
    int nW = tid & 127, kb16 = (tid >> 7) * 16;   // thread covers k = kb16 + i
    size_t wcol = (size_t)((n0 + nW) >> 6) * DMODEL * 64 + ((n0 + nW) & 63);
    int wbase = nW * 40 + kb16;
    f32x4 acc[4][4];
#pragma unroll
    for (int mi = 0; mi < 4; mi++)
#pragma unroll
        for (int ni = 0; ni < 4; ni++) acc[mi][ni] = zero4();
    const bf16* Ah = hA_h + (size_t)m0 * DMODEL;
    const bf16* Al = hA_l + (size_t)m0 * DMODEL;
    bf16x8 rAh0, rAh1, rAl0, rAl1;
    float wv[16];
    rAh0 = *(const bf16x8*)&Ah[(size_t)r_a * DMODEL + c_a];
    rAh1 = *(const bf16x8*)&Ah[(size_t)(r_a + 64) * DMODEL + c_a];
    rAl0 = *(const bf16x8*)&Al[(size_t)r_a * DMODEL + c_a];
    rAl1 = *(const bf16x8*)&Al[(size_t)(r_a + 64) * DMODEL + c_a];
#pragma unroll
    for (int i = 0; i < 16; i++) wv[i] = W[wcol + (size_t)(kb16 + i) * 64];
    *(bf16x8*)&lah[r_a * 40 + c_a] = rAh0;
    *(bf16x8*)&lah[(r_a + 64) * 40 + c_a] = rAh1;
    *(bf16x8*)&lal[r_a * 40 + c_a] = rAl0;
    *(bf16x8*)&lal[(r_a + 64) * 40 + c_a] = rAl1;
    wstore_hilo(lbh, lbl, wbase, wv);
    const int nk = DMODEL / 32;
    for (int ki = 0; ki < nk; ki++) {
        __syncthreads();
        int cur = (ki & 1) * TILE_E, nxt = ((ki + 1) & 1) * TILE_E;
        if (ki + 1 < nk) {
            int k0 = (ki + 1) * 32;
            rAh0 = *(const bf16x8*)&Ah[(size_t)r_a * DMODEL + k0 + c_a];
            rAh1 = *(const bf16x8*)&Ah[(size_t)(r_a + 64) * DMODEL + k0 + c_a];
            rAl0 = *(const bf16x8*)&Al[(size_t)r_a * DMODEL + k0 + c_a];
            rAl1 = *(const bf16x8*)&Al[(size_t)(r_a + 64) * DMODEL + k0 + c_a];
#pragma unroll
            for (int i = 0; i < 16; i++)
                wv[i] = W[wcol + (size_t)(k0 + kb16 + i) * 64];
        }
        gemm_step3(lah + cur, lal + cur, lbh + cur, lbl + cur, wm, wn, row16, quad, acc);
        if (ki + 1 < nk) {
            *(bf16x8*)&lah[nxt + r_a * 40 + c_a] = rAh0;
            *(bf16x8*)&lah[nxt + (r_a + 64) * 40 + c_a] = rAh1;
            *(bf16x8*)&lal[nxt + r_a * 40 + c_a] = rAl0;
            *(bf16x8*)&lal[nxt + (r_a + 64) * 40 + c_a] = rAl1;
            wstore_hilo(lbh + nxt, lbl + nxt, wbase, wv);
        }
    }
#pragma unroll
    for (int mi = 0; mi < 4; mi++) {
        int rowl = wm * 64 + mi * 16 + quad * 4;
#pragma unroll
        for (int ni = 0; ni < 4; ni++) {
            int col = n0 + wn * 64 + ni * 16 + row16;
            int hhd = col >> 6, s = col & 63;
#pragma unroll
            for (int r = 0; r < 4; r++) {
                int gm = m0 + rowl + r;
                int bb = gm >> 10, t = gm & 1023;
                size_t oi = (((size_t)bb * NHEAD + hhd) * TSEQ + t) * 64 + s;
                float val = acc[mi][ni][r];
                bf16 hi = (bf16)val;
                obh[oi] = hi;
                obl[oi] = (bf16)(val - (float)hi);
            }
        }
    }
}

// ---------------- flash attention (split bf16x3), causal ----------------
__global__ __launch_bounds__(256) void attn_kernel(const bf16* __restrict__ qhb,
        const bf16* __restrict__ qlb, const bf16* __restrict__ khb,
        const bf16* __restrict__ klb, const bf16* __restrict__ vhb,
        const bf16* __restrict__ vlb, bf16* __restrict__ aoh,
        bf16* __restrict__ aol) {
    __shared__ alignas(16) bf16 kt_h[64 * 72];
    __shared__ alignas(16) bf16 kt_l[64 * 72];
    __shared__ alignas(16) bf16 vt_h[64 * 72];
    __shared__ alignas(16) bf16 vt_l[64 * 72];
    __shared__ alignas(16) bf16 p_h[4][16 * 72];
    __shared__ alignas(16) bf16 p_l[4][16 * 72];
    int qt = blockIdx.x, bh = blockIdx.y;
    int b = bh / NHEAD, hh = bh % NHEAD;
    int tid = threadIdx.x, lane = tid & 63, w = tid >> 6;
    int row16 = lane & 15, quad = lane >> 4;
    const bf16* qph = qhb + (size_t)bh * TSEQ * 64;
    const bf16* qpl = qlb + (size_t)bh * TSEQ * 64;
    const bf16* kph = khb + (size_t)bh * TSEQ * 64;
    const bf16* kpl = klb + (size_t)bh * TSEQ * 64;
    const bf16* vph = vhb + (size_t)bh * TSEQ * 64;
    const bf16* vpl = vlb + (size_t)bh * TSEQ * 64;
    int qrow = qt * 64 + w * 16 + row16;
    bf16x8 aq_h[2], aq_l[2];
#pragma unroll
    for (int kk = 0; kk < 2; kk++) {
        aq_h[kk] = *(const bf16x8*)&qph[(size_t)qrow * 64 + kk * 32 + quad * 8];
        aq_l[kk] = *(const bf16x8*)&qpl[(size_t)qrow * 64 + kk * 32 + quad * 8];
    }
    f32x4 o[4];
    float m_i[4], l_i[4];
#pragma unroll
    for (int i = 0; i < 4; i++) { o[i] = zero4(); m_i[i] = -INFINITY; l_i[i] = 0.f; }
    const float sc = 0.03608439182435161f;  // 768^-0.5
    for (int kt = 0; kt <= qt; kt++) {
        __syncthreads();
#pragma unroll
        for (int i = 0; i < 2; i++) {
            int chunk = tid + i * 256;
            int r = chunk >> 3, c = (chunk & 7) << 3;
            size_t gi = (size_t)(kt * 64 + r) * 64 + c;
            *(bf16x8*)&kt_h[r * 72 + c] = *(const bf16x8*)&kph[gi];
            *(bf16x8*)&kt_l[r * 72 + c] = *(const bf16x8*)&kpl[gi];
        }
        // V transpose: thread handles (s, 4 consecutive tk) -> b64 writes
#pragma unroll
        for (int u = 0; u < 4; u++) {
            int unit = tid + u * 256;
            int s = unit & 63, tg = unit >> 6;   // tg 0..15
            bf16x4 ph, pl;
#pragma unroll
            for (int j = 0; j < 4; j++) {
                size_t gi = (size_t)(kt * 64 + tg * 4 + j) * 64 + s;
                ph[j] = vph[gi];
                pl[j] = vpl[gi];
            }
            *(bf16x4*)&vt_h[s * 72 + tg * 4] = ph;
            *(bf16x4*)&vt_l[s * 72 + tg * 4] = pl;
        }
        __syncthreads();
        f32x4 sacc[4];
#pragma unroll
        for (int ni = 0; ni < 4; ni++) {
            sacc[ni] = zero4();
#pragma unroll
            for (int kk = 0; kk < 2; kk++) {
                int ro = (ni * 16 + row16) * 72 + kk * 32 + quad * 8;
                bf16x8 bk_h = *(const bf16x8*)&kt_h[ro];
                bf16x8 bk_l = *(const bf16x8*)&kt_l[ro];
                sacc[ni] = mfma16(aq_h[kk], bk_h, sacc[ni]);
                sacc[ni] = mfma16(aq_h[kk], bk_l, sacc[ni]);
                sacc[ni] = mfma16(aq_l[kk], bk_h, sacc[ni]);
            }
        }
        float mrow[4];
#pragma unroll
        for (int r = 0; r < 4; r++) mrow[r] = -INFINITY;
        int tq_b = qt * 64 + w * 16 + quad * 4;
#pragma unroll
        for (int ni = 0; ni < 4; ni++) {
            int tkg = kt * 64 + ni * 16 + row16;
#pragma unroll
            for (int r = 0; r < 4; r++) {
                float sv = sacc[ni][r] * sc;
                if (tkg > tq_b + r) sv = -INFINITY;
                sacc[ni][r] = sv;
                mrow[r] = fmaxf(mrow[r], sv);
            }
        }
#pragma unroll
        for (int r = 0; r < 4; r++) {
#pragma unroll
            for (int off = 8; off > 0; off >>= 1)
                mrow[r] = fmaxf(mrow[r], __shfl_xor(mrow[r], off, 16));
        }
        float alpha[4], rsum[4];
#pragma unroll
        for (int r = 0; r < 4; r++) {
            float nm = fmaxf(m_i[r], mrow[r]);
            alpha[r] = __expf(m_i[r] - nm);
            m_i[r] = nm;
            rsum[r] = 0.f;
        }
#pragma unroll
        for (int ni = 0; ni < 4; ni++)
#pragma unroll
            for (int r = 0; r < 4; r++) {
                float p = __expf(sacc[ni][r] - m_i[r]);
                sacc[ni][r] = p;
                rsum[r] += p;
            }
#pragma unroll
        for (int r = 0; r < 4; r++) {
#pragma unroll
            for (int off = 8; off > 0; off >>= 1)
                rsum[r] += __shfl_xor(rsum[r], off, 16);
            l_i[r] = l_i[r] * alpha[r] + rsum[r];
        }
#pragma unroll
        for (int ni = 0; ni < 4; ni++)
#pragma unroll
            for (int r = 0; r < 4; r++) o[ni][r] *= alpha[r];
#pragma unroll
        for (int ni = 0; ni < 4; ni++)
#pragma unroll
            for (int r = 0; r < 4; r++) {
                float p = sacc[ni][r];
                bf16 hi = (bf16)p;
                int po = (quad * 4 + r) * 72 + ni * 16 + row16;
                p_h[w][po] = hi;
                p_l[w][po] = (bf16)(p - (float)hi);
            }
        __syncthreads();
        bf16x8 ap_h[2], ap_l[2];
#pragma unroll
        for (int kk = 0; kk < 2; kk++) {
            ap_h[kk] = *(const bf16x8*)&p_h[w][row16 * 72 + kk * 32 + quad * 8];
            ap_l[kk] = *(const bf16x8*)&p_l[w][row16 * 72 + kk * 32 + quad * 8];
        }
#pragma unroll
        for (int ni = 0; ni < 4; ni++)
#pragma unroll
            for (int kk = 0; kk < 2; kk++) {
                int ro = (ni * 16 + row16) * 72 + kk * 32 + quad * 8;
                bf16x8 bv_h = *(const bf16x8*)&vt_h[ro];
                bf16x8 bv_l = *(const bf16x8*)&vt_l[ro];
                o[ni] = mfma16(ap_h[kk], bv_h, o[ni]);
                o[ni] = mfma16(ap_h[kk], bv_l, o[ni]);
                o[ni] = mfma16(ap_l[kk], bv_h, o[ni]);
            }
    }
    int t = qt * 64 + w * 16 + quad * 4;
#pragma unroll
    for (int ni = 0; ni < 4; ni++) {
        int col = hh * 64 + ni * 16 + row16;
#pragma unroll
        for (int r = 0; r < 4; r++) {
            float val = o[ni][r] / l_i[r];
            size_t n = (size_t)b * TSEQ + t + r;
            bf16 hi = (bf16)val;
            aoh[n * DMODEL + col] = hi;
            aol[n * DMODEL + col] = (bf16)(val - (float)hi);
        }
    }
}

// ---------------- proj GEMM (split bf16x3, prefetched) ----------------
__global__ __launch_bounds__(256) void proj_gemm(const bf16* __restrict__ aInH,
        const bf16* __restrict__ aInL,
        const float* __restrict__ Wp, const float* __restrict__ bp,
        const float* __restrict__ x, float* __restrict__ x1) {
    __shared__ alignas(16) bf16 lah[2 * TILE_E];
    __shared__ alignas(16) bf16 lal[2 * TILE_E];
    __shared__ alignas(16) bf16 lbh[2 * TILE_E];
    __shared__ alignas(16) bf16 lbl[2 * TILE_E];
    int tid = threadIdx.x;
    int m0 = blockIdx.y * 128, n0 = blockIdx.x * 128;
    int lane = tid & 63, w = tid >> 6, row16 = lane & 15, quad = lane >> 4;
    int wm = w >> 1, wn = w & 1;
    int r_a = tid >> 2, c_a = (tid & 3) << 3;
    int nW = tid & 127, kb16 = (tid >> 7) * 16;
    int wbase = nW * 40 + kb16;
    f32x4 acc[4][4];
#pragma unroll
    for (int mi = 0; mi < 4; mi++)
#pragma unroll
        for (int ni = 0; ni < 4; ni++) acc[mi][ni] = zero4();
    const bf16* Ah = aInH + (size_t)m0 * DMODEL;
    const bf16* Al = aInL + (size_t)m0 * DMODEL;
    bf16x8 rAh0, rAh1, rAl0, rAl1;
    float wv[16];
    rAh0 = *(const bf16x8*)&Ah[(size_t)r_a * DMODEL + c_a];
    rAh1 = *(const bf16x8*)&Ah[(size_t)(r_a + 64) * DMODEL + c_a];
    rAl0 = *(const bf16x8*)&Al[(size_t)r_a * DMODEL + c_a];
    rAl1 = *(const bf16x8*)&Al[(size_t)(r_a + 64) * DMODEL + c_a];
#pragma unroll
    for (int i = 0; i < 16; i++)
        wv[i] = Wp[(size_t)(kb16 + i) * DMODEL + n0 + nW];
    *(bf16x8*)&lah[r_a * 40 + c_a] = rAh0;
    *(bf16x8*)&lah[(r_a + 64) * 40 + c_a] = rAh1;
    *(bf16x8*)&lal[r_a * 40 + c_a] = rAl0;
    *(bf16x8*)&lal[(r_a + 64) * 40 + c_a] = rAl1;
    wstore_hilo(lbh, lbl, wbase, wv);
    const int nk = DMODEL / 32;
    for (int ki = 0; ki < nk; ki++) {
        __syncthreads();
        int cur = (ki & 1) * TILE_E, nxt = ((ki + 1) & 1) * TILE_E;
        if (ki + 1 < nk) {
            int k0 = (ki + 1) * 32;
            rAh0 = *(const bf16x8*)&Ah[(size_t)r_a * DMODEL + k0 + c_a];
            rAh1 = *(const bf16x8*)&Ah[(size_t)(r_a + 64) * DMODEL + k0 + c_a];
            rAl0 = *(const bf16x8*)&Al[(size_t)r_a * DMODEL + k0 + c_a];
            rAl1 = *(const bf16x8*)&Al[(size_t)(r_a + 64) * DMODEL + k0 + c_a];
#pragma unroll
            for (int i = 0; i < 16; i++)
                wv[i] = Wp[(size_t)(k0 + kb16 + i) * DMODEL + n0 + nW];
        }
        gemm_step3(lah + cur, lal + cur, lbh + cur, lbl + cur, wm, wn, row16, quad, acc);
        if (ki + 1 < nk) {
            *(bf16x8*)&lah[nxt + r_a * 40 + c_a] = rAh0;
            *(bf16x8*)&lah[nxt + (r_a + 64) * 40 + c_a] = rAh1;
            *(bf16x8*)&lal[nxt + r_a * 40 + c_a] = rAl0;
            *(bf16x8*)&lal[nxt + (r_a + 64) * 40 + c_a] = rAl1;
            wstore_hilo(lbh + nxt, lbl + nxt, wbase, wv);
        }
    }
#pragma unroll
    for (int mi = 0; mi < 4; mi++) {
        int rowl = wm * 64 + mi * 16 + quad * 4;
#pragma unroll
        for (int ni = 0; ni < 4; ni++) {
            int col = n0 + wn * 64 + ni * 16 + row16;
#pragma unroll
            for (int r = 0; r < 4; r++) {
                int gm = m0 + rowl + r;
                x1[(size_t)gm * DMODEL + col] =
                    acc[mi][ni][r] + bp[col] + x[(size_t)gm * DMODEL + col];
            }
        }
    }
}

// ---------------- LN2 + gate argmax + expert counting ----------------
__global__ __launch_bounds__(256) void ln2_gate_kernel(const float* __restrict__ x1,
        const float* __restrict__ g, const float* __restrict__ b,
        const float* __restrict__ Wg, bf16* __restrict__ h2,
        int* __restrict__ sel, int* __restrict__ counts) {
    __shared__ float red[4];
    __shared__ float glog[8];
    int row = blockIdx.x, tid = threadIdx.x;
    if (tid < 8) glog[tid] = 0.f;
    const float* xr = x1 + (size_t)row * DMODEL;
    float v[3];
#pragma unroll
    for (int i = 0; i < 3; i++) v[i] = xr[tid + i * 256];
    float s = block_sum(v[0] + v[1] + v[2], red, tid);
    float mu = s * (1.f / DMODEL);
    float qv = 0.f;
#pragma unroll
    for (int i = 0; i < 3; i++) { float d = v[i] - mu; qv += d * d; }
    qv = block_sum(qv, red, tid);
    float rstd = 1.0f / sqrtf(qv * (1.f / DMODEL) + 1e-5f);
    float ga[8];
#pragma unroll
    for (int e = 0; e < 8; e++) ga[e] = 0.f;
#pragma unroll
    for (int i = 0; i < 3; i++) {
        int d = tid + i * 256;
        float hv = (v[i] - mu) * rstd * g[d] + b[d];
        h2[(size_t)row * DMODEL + d] = (bf16)hv;
        const float* wgr = Wg + (size_t)d * NEXP;
#pragma unroll
        for (int e = 0; e < 8; e++) ga[e] += hv * wgr[e];
    }
#pragma unroll
    for (int e = 0; e < 8; e++)
#pragma unroll
        for (int off = 32; off > 0; off >>= 1) ga[e] += __shfl_down(ga[e], off, 64);
    if ((tid & 63) == 0)
#pragma unroll
        for (int e = 0; e < 8; e++) atomicAdd(&glog[e], ga[e]);
    __syncthreads();
    if (tid == 0) {
        float best = glog[0];
        int bi = 0;
#pragma unroll
        for (int e = 1; e < 8; e++)
            if (glog[e] > best) { best = glog[e]; bi = e; }
        sel[row] = bi;
        atomicAdd(&counts[bi], 1);
    }
}

// ---------------- scatter (scan folded in) ----------------
__global__ void scatter_kernel(const int* __restrict__ sel, const int* __restrict__ counts,
                               int* __restrict__ cursor, int* __restrict__ perm) {
    int n = blockIdx.x * blockDim.x + threadIdx.x;
    if (n >= N_TOK) return;
    int e = sel[n];
    int off = 0;
    for (int i = 0; i < NEXP; i++) off += (i < e) ? counts[i] : 0;
    int pos = atomicAdd(&cursor[e], 1);
    perm[off + pos] = n;
}

// ---------------- MoE GEMM1 (prefetched): hid = relu(h2[perm] @ W1[e] + b1[e]) ----------------
__global__ __launch_bounds__(256) void moe1_gemm(const bf16* __restrict__ h2,
        const float* __restrict__ W1, const float* __restrict__ b1,
        const int* __restrict__ counts, const int* __restrict__ perm,
        bf16* __restrict__ hid) {
    int e = blockIdx.z;
    int cnt = counts[e];
    int rt = blockIdx.y;
    if (rt * 128 >= cnt) return;
    int off = 0;
    for (int i = 0; i < NEXP; i++) off += (i < e) ? counts[i] : 0;
    int n0 = blockIdx.x * 128;
    const float* W = W1 + (size_t)e * DMODEL * DFF;
    __shared__ alignas(16) bf16 la[2 * TILE_E];
    __shared__ alignas(16) bf16 lb[2 * TILE_E];
    int tid = threadIdx.x;
    int lane = tid & 63, w = tid >> 6, row16 = lane & 15, quad = lane >> 4;
    int wm = w >> 1, wn = w & 1;
    int r_a = tid >> 2, c_a = (tid & 3) << 3;
    int nW = tid & 127, kb16 = (tid >> 7) * 16;
    int wbase = nW * 40 + kb16;
    int tok0 = perm[off + min(rt * 128 + r_a, cnt - 1)];
    int tok1 = perm[off + min(rt * 128 + r_a + 64, cnt - 1)];
    const bf16* a0 = h2 + (size_t)tok0 * DMODEL;
    const bf16* a1 = h2 + (size_t)tok1 * DMODEL;
    f32x4 acc[4][4];
#pragma unroll
    for (int mi = 0; mi < 4; mi++)
#pragma unroll
        for (int ni = 0; ni < 4; ni++) acc[mi][ni] = zero4();
    bf16x8 rA0, rA1;
    float wv[16];
    rA0 = *(const bf16x8*)&a0[c_a];
    rA1 = *(const bf16x8*)&a1[c_a];
#pragma unroll
    for (int i = 0; i < 16; i++)
        wv[i] = W[(size_t)(kb16 + i) * DFF + n0 + nW];
    *(bf16x8*)&la[r_a * 40 + c_a] = rA0;
    *(bf16x8*)&la[(r_a + 64) * 40 + c_a] = rA1;
    wstore1(lb, wbase, wv);
    const int nk = DMODEL / 32;
    for (int ki = 0; ki < nk; ki++) {
        __syncthreads();
        int cur = (ki & 1) * TILE_E, nxt = ((ki + 1) & 1) * TILE_E;
        if (ki + 1 < nk) {
            int k0 = (ki + 1) * 32;
            rA0 = *(const bf16x8*)&a0[k0 + c_a];
            rA1 = *(const bf16x8*)&a1[k0 + c_a];
#pragma unroll
            for (int i = 0; i < 16; i++)
                wv[i] = W[(size_t)(k0 + kb16 + i) * DFF + n0 + nW];
        }
        gemm_step1(la + cur, lb + cur, wm, wn, row16, quad, acc);
        if (ki + 1 < nk) {
            *(bf16x8*)&la[nxt + r_a * 40 + c_a] = rA0;
            *(bf16x8*)&la[nxt + (r_a + 64) * 40 + c_a] = rA1;
            wstore1(lb + nxt, wbase, wv);
        }
    }
#pragma unroll
    for (int mi = 0; mi < 4; mi++) {
        int rowl = wm * 64 + mi * 16 + quad * 4;
#pragma unroll
        for (int ni = 0; ni < 4; ni++) {
            int col = n0 + wn * 64 + ni * 16 + row16;
#pragma unroll
            for (int r = 0; r < 4; r++) {
                int lr = rowl + r;
                if (rt * 128 + lr < cnt) {
                    float val = acc[mi][ni][r] + b1[(size_t)e * DFF + col];
                    val = fmaxf(val, 0.f);
                    hid[(size_t)(off + rt * 128 + lr) * DFF + col] = (bf16)val;
                }
            }
        }
    }
}

// ---------------- MoE GEMM2 (prefetched, split-K=4, atomic) ----------------
__global__ __launch_bounds__(256) void moe2_gemm(const bf16* __restrict__ hid,
        const float* __restrict__ W2, const float* __restrict__ b2,
        const int* __restrict__ counts, const int* __restrict__ perm,
        const float* __restrict__ x1, float* __restrict__ out) {
    int ez = blockIdx.z;
    int e = ez & 7, ks = ez >> 3;       // 8 experts x 4 K-slices
    int cnt = counts[e];
    int rt = blockIdx.y;
    if (rt * 128 >= cnt) return;
    int off = 0;
    for (int i = 0; i < NEXP; i++) off += (i < e) ? counts[i] : 0;
    int n0 = blockIdx.x * 128;
    const float* W = W2 + (size_t)e * DFF * DMODEL;
    __shared__ alignas(16) bf16 la[2 * TILE_E];
    __shared__ alignas(16) bf16 lb[2 * TILE_E];
    int tid = threadIdx.x;
    int lane = tid & 63, w = tid >> 6, row16 = lane & 15, quad = lane >> 4;
    int wm = w >> 1, wn = w & 1;
    int r_a = tid >> 2, c_a = (tid & 3) << 3;
    int nW = tid & 127, kb16 = (tid >> 7) * 16;
    int wbase = nW * 40 + kb16;
    const bf16* a0 = hid + (size_t)min(off + rt * 128 + r_a, N_TOK - 1) * DFF;
    const bf16* a1 = hid + (size_t)min(off + rt * 128 + r_a + 64, N_TOK - 1) * DFF;
    f32x4 acc[4][4];
#pragma unroll
    for (int mi = 0; mi < 4; mi++)
#pragma unroll
        for (int ni = 0; ni < 4; ni++) acc[mi][ni] = zero4();
    const int kst = ks * (DFF / 4);
    bf16x8 rA0, rA1;
    float wv[16];
    rA0 = *(const bf16x8*)&a0[kst + c_a];
    rA1 = *(const bf16x8*)&a1[kst + c_a];
#pragma unroll
    for (int i = 0; i < 16; i++)
        wv[i] = W[(size_t)(kst + kb16 + i) * DMODEL + n0 + nW];
    *(bf16x8*)&la[r_a * 40 + c_a] = rA0;
    *(bf16x8*)&la[(r_a + 64) * 40 + c_a] = rA1;
    wstore1(lb, wbase, wv);
    const int nk = (DFF / 4) / 32;
    for (int ki = 0; ki < nk; ki++) {
        __syncthreads();
        int cur = (ki & 1) * TILE_E, nxt = ((ki + 1) & 1) * TILE_E;
        if (ki + 1 < nk) {
            int k0 = kst + (ki + 1) * 32;
            rA0 = *(const bf16x8*)&a0[k0 + c_a];
            rA1 = *(const bf16x8*)&a1[k0 + c_a];
#pragma unroll
            for (int i = 0; i < 16; i++)
                wv[i] = W[(size_t)(k0 + kb16 + i) * DMODEL + n0 + nW];
        }
        gemm_step1(la + cur, lb + cur, wm, wn, row16, quad, acc);
        if (ki + 1 < nk) {
            *(bf16x8*)&la[nxt + r_a * 40 + c_a] = rA0;
            *(bf16x8*)&la[nxt + (r_a + 64) * 40 + c_a] = rA1;
            wstore1(lb + nxt, wbase, wv);
        }
    }
#pragma unroll
    for (int mi = 0; mi < 4; mi++) {
        int rowl = wm * 64 + mi * 16 + quad * 4;
#pragma unroll
        for (int ni = 0; ni < 4; ni++) {
            int col = n0 + wn * 64 + ni * 16 + row16;
#pragma unroll
            for (int r = 0; r < 4; r++) {
                int lr = rowl + r;
                if (rt * 128 + lr < cnt) {
                    int n = perm[off + rt * 128 + lr];
                    float val = acc[mi][ni][r];
                    if (ks == 0)
                        val += b2[(size_t)e * DMODEL + col] + x1[(size_t)n * DMODEL + col];
                    atomicAdd(&out[(size_t)n * DMODEL + col], val);
                }
            }
        }
    }
}

// ---------------- launch ----------------
extern "C" void kernel_launch(void* const* d_in, const int* in_sizes, int n_in,
                              void* d_out, int out_size, void* d_ws, size_t ws_size,
                              hipStream_t stream) {
    const float* x    = (const float*)d_in[0];
    const float* ln1g = (const float*)d_in[1];
    const float* ln1b = (const float*)d_in[2];
    const float* ln2g = (const float*)d_in[3];
    const float* ln2b = (const float*)d_in[4];
    const float* Wq   = (const float*)d_in[5];
    const float* Wk   = (const float*)d_in[6];
    const float* Wv   = (const float*)d_in[7];
    const float* Wp   = (const float*)d_in[8];
    const float* bp   = (const float*)d_in[9];
    const float* Wg   = (const float*)d_in[10];
    const float* W1   = (const float*)d_in[11];
    const float* b1   = (const float*)d_in[12];
    const float* W2   = (const float*)d_in[13];
    const float* b2   = (const float*)d_in[14];
    float* out = (float*)d_out;

    char* ws = (char*)d_ws;
    size_t off = 0;
    const size_t SZ = (size_t)N_TOK * DMODEL * 2;
    bf16* h1h = (bf16*)(ws + off); off += SZ;
    bf16* h1l = (bf16*)(ws + off); off += SZ;
    bf16* qh  = (bf16*)(ws + off); off += SZ;
    bf16* ql  = (bf16*)(ws + off); off += SZ;
    bf16* kh  = (bf16*)(ws + off); off += SZ;
    bf16* kl  = (bf16*)(ws + off); off += SZ;
    bf16* vh  = (bf16*)(ws + off); off += SZ;
    bf16* vl  = (bf16*)(ws + off); off += SZ;
    bf16* aoh = (bf16*)(ws + off); off += SZ;
    bf16* aol = (bf16*)(ws + off); off += SZ;
    float* x1 = (float*)(ws + off); off += (size_t)N_TOK * DMODEL * 4;
    bf16* h2  = (bf16*)(ws + off); off += SZ;
    bf16* hid = (bf16*)(ws + off); off += (size_t)N_TOK * DFF * 2;
    int* counts  = (int*)(ws + off); off += 8 * 4;
    int* cursor  = (int*)(ws + off); off += 8 * 4;
    int* sel     = (int*)(ws + off); off += (size_t)N_TOK * 4;
    int* perm    = (int*)(ws + off); off += (size_t)N_TOK * 4;

    ln1_kernel<<<N_TOK, 256, 0, stream>>>(x, ln1g, ln1b, h1h, h1l, counts, out);
    qkv_gemm<<<dim3(18, 16), 256, 0, stream>>>(h1h, h1l, Wq, Wk, Wv, qh, ql, kh, kl, vh, vl);
    attn_kernel<<<dim3(16, 24), 256, 0, stream>>>(qh, ql, kh, kl, vh, vl, aoh, aol);
    proj_gemm<<<dim3(6, 16), 256, 0, stream>>>(aoh, aol, Wp, bp, x, x1);
    ln2_gate_kernel<<<N_TOK, 256, 0, stream>>>(x1, ln2g, ln2b, Wg, h2, sel, counts);
    scatter_kernel<<<8, 256, 0, stream>>>(sel, counts, cursor, perm);
    moe1_gemm<<<dim3(24, 16, 8), 256, 0, stream>>>(h2, W1, b1, counts, perm, hid);
    moe2_gemm<<<dim3(6, 16, 32), 256, 0, stream>>>(hid, W2, b2, counts, perm, x1, out);
}